// Round 4
// baseline (1901.999 us; speedup 1.0000x reference)
//
#include <hip/hip_runtime.h>
#include <cstdint>
#include <cstddef>

#define N_NODES 100000
#define N_EDGES 3200000
#define MPAD    100096   // 782 * 128
#define HID     256
#define NBUCK   196
#define BSH     9
#define BSTRIDE 18432
#define N_HALF  50000
#define NGRP    6250     // node groups of 16 (one 1024-thr block each); 6250*16 = 100000

typedef _Float16 f16;
typedef _Float16 f16x8 __attribute__((ext_vector_type(8)));
typedef float    f32x4 __attribute__((ext_vector_type(4)));

union F16x2 { unsigned u; f16 h[2]; };
__device__ inline void unpack2(unsigned u, float& a, float& b) {
    F16x2 x; x.u = u; a = (float)x.h[0]; b = (float)x.h[1];
}
__device__ inline unsigned pack2(float a, float b) {
    F16x2 x; x.h[0] = (f16)a; x.h[1] = (f16)b; return x.u;
}

// ---------------- CSR build: bucketed counting sort ----------------
__global__ __launch_bounds__(256) void k_bucketA(const int* __restrict__ src,
                                                 const int* __restrict__ dst,
                                                 unsigned* __restrict__ pairs,
                                                 int* __restrict__ nb, int e) {
    __shared__ int hist[NBUCK];
    __shared__ int lbase[NBUCK];
    __shared__ int lcur[NBUCK];
    const int t = threadIdx.x;
    for (int i = t; i < NBUCK; i += 256) hist[i] = 0;
    __syncthreads();
    const int e0 = blockIdx.x * 4096;
    bool v[16]; int d[16], s[16];
#pragma unroll
    for (int i = 0; i < 16; ++i) {
        int idx = e0 + i * 256 + t;
        v[i] = idx < e;
        d[i] = v[i] ? dst[idx] : 0;
        s[i] = v[i] ? src[idx] : 0;
    }
#pragma unroll
    for (int i = 0; i < 16; ++i)
        if (v[i]) atomicAdd(&hist[d[i] >> BSH], 1);
    __syncthreads();
    for (int i = t; i < NBUCK; i += 256) {
        int h = hist[i];
        lbase[i] = h ? atomicAdd(&nb[i], h) : 0;
        lcur[i] = 0;
    }
    __syncthreads();
#pragma unroll
    for (int i = 0; i < 16; ++i) {
        if (v[i]) {
            int b = d[i] >> BSH;
            int p = atomicAdd(&lcur[b], 1);
            unsigned packed = ((unsigned)(d[i] & 511) << 17) | (unsigned)s[i];
            pairs[(size_t)b * BSTRIDE + lbase[b] + p] = packed;
        }
    }
}

__global__ void k_scan196(const int* __restrict__ nb, int* __restrict__ bbase,
                          int* __restrict__ rowptrN) {
    __shared__ int s[256];
    int t = threadIdx.x;
    int v = (t < NBUCK) ? nb[t] : 0;
    s[t] = v;
    __syncthreads();
    for (int off = 1; off < 256; off <<= 1) {
        int u = (t >= off) ? s[t - off] : 0;
        __syncthreads();
        s[t] += u;
        __syncthreads();
    }
    if (t < NBUCK) bbase[t] = s[t] - v;
    if (t == 0) *rowptrN = N_EDGES;
}

__global__ __launch_bounds__(256) void k_bucketB(const unsigned* __restrict__ pairs,
                                                 const int* __restrict__ nb,
                                                 const int* __restrict__ bbase,
                                                 int* __restrict__ rowptr,
                                                 int* __restrict__ colidx) {
    __shared__ int deg[512];
    __shared__ int sc[512];
    __shared__ int cur[512];
    const int b = blockIdx.x, t = threadIdx.x;
    const int cnt = nb[b], base = bbase[b];
    const unsigned* P = pairs + (size_t)b * BSTRIDE;
    deg[t] = 0; deg[t + 256] = 0;
    __syncthreads();
    for (int i = t; i < cnt; i += 256) atomicAdd(&deg[P[i] >> 17], 1);
    __syncthreads();
    sc[t] = deg[t]; sc[t + 256] = deg[t + 256];
    __syncthreads();
    for (int off = 1; off < 512; off <<= 1) {
        int a0 = (t >= off) ? sc[t - off] : 0;
        int a1 = (t + 256 >= off) ? sc[t + 256 - off] : 0;
        __syncthreads();
        sc[t] += a0; sc[t + 256] += a1;
        __syncthreads();
    }
    int node0 = b << BSH;
#pragma unroll
    for (int rep = 0; rep < 2; ++rep) {
        int i = t + rep * 256;
        int excl = base + sc[i] - deg[i];
        cur[i] = excl;
        int node = node0 + i;
        if (node < N_NODES) rowptr[node] = excl;
    }
    __syncthreads();
    for (int i = t; i < cnt; i += 256) {
        unsigned p = P[i];
        int pos = atomicAdd(&cur[p >> 17], 1);
        colidx[pos] = (int)(p & 0x1FFFF);
    }
}

// Partition each row into (src < N_HALF | src >= N_HALF); split[i] = lo count.
// Any split is correct (each edge visited exactly once across the 2 halves);
// partition only buys locality. deg>64 rows: split=deg (all in half 0).
__global__ void k_part(const int* __restrict__ rp, int* __restrict__ ci,
                       int* __restrict__ split, int n) {
    int gw = (blockIdx.x * 256 + threadIdx.x) >> 6;
    if (gw >= n) return;
    int lane = threadIdx.x & 63;
    int s = rp[gw], e = rp[gw + 1];
    int deg = e - s;
    if (deg > 64) { if (lane == 0) split[gw] = deg; return; }
    int v = (lane < deg) ? ci[s + lane] : 0;
    bool lo = (lane < deg) && (v < N_HALF);
    bool hi = (lane < deg) && !lo;
    unsigned long long mlo = __ballot(lo);
    unsigned long long mhi = __ballot(hi);
    unsigned long long below = (lane == 63) ? ~0ull >> 1 : ((1ull << lane) - 1);
    int cnt = __popcll(mlo);
    int pos = lo ? (int)__popcll(mlo & below) : cnt + (int)__popcll(mhi & below);
    if (lane < deg) ci[s + pos] = v;
    if (lane == 0) split[gw] = cnt;
}

// ---------------- dtype prep ----------------
// x fp32 [N][128] -> strips [4][MPAD][32] f16
__global__ void k_cvt(const float2* __restrict__ x, unsigned* __restrict__ o, int n) {
    int t = blockIdx.x * 256 + threadIdx.x;
    if (t >= n) return;
    float2 v = x[t];
    int node = t >> 6, p = t & 63;
    o[((size_t)(p >> 4) * MPAD + node) * 16 + (p & 15)] = pack2(v.x, v.y);
}

__global__ void k_foldw1(const float* __restrict__ W, const float* __restrict__ b1,
                         const float* __restrict__ gm, const float* __restrict__ bt,
                         const float* __restrict__ mu, const float* __restrict__ vr,
                         f16* __restrict__ Wt, float* __restrict__ bias, int K) {
    int t = blockIdx.x * 256 + threadIdx.x;
    if (t >= K * 256) return;
    int n = t & 255, k = t >> 8;
    float sc = gm[n] * rsqrtf(vr[n] + 1e-5f);
    Wt[n * K + k] = (f16)(W[t] * sc);
    if (k == 0) bias[n] = (b1[n] - mu[n]) * sc + bt[n];
}

__global__ void k_transb(const float* __restrict__ W, f16* __restrict__ Wt) {
    int t = blockIdx.x * 256 + threadIdx.x;
    int n = t & 255, k = t >> 8;
    Wt[n * 256 + k] = (f16)W[t];
}

// ---------------- strip aggregation ----------------
// H,Z strip layout [NC][MPAD][32] f16 (64 B rows). One pass = (chunk, half):
// touched table slice = 50K x 64 B = 3.2 MB -> L2-resident per XCD.
// Wave per node: j=lane>>3 edge slot, q=lane&7 byte-octet of the row.
// FIRSTHALF launch writes z (+self); second launch accumulates (stream-ordered).
template <int NC, bool FIRSTHALF>
__global__ __launch_bounds__(1024) void k_aggs(const f16* __restrict__ H,
                                               const int* __restrict__ rp,
                                               const int* __restrict__ ci,
                                               const int* __restrict__ split,
                                               f16* __restrict__ Z) {
    int chunk = blockIdx.x / NGRP;
    int grp   = blockIdx.x % NGRP;
    int w = threadIdx.x >> 6, lane = threadIdx.x & 63;
    int i = grp * 16 + w;              // < 100000 exactly
    int j = lane >> 3, q = lane & 7;
    const f16* B = H + (size_t)chunk * (MPAD * 32);
    int s0 = rp[i], sp = split[i];
    int s = FIRSTHALF ? s0 : s0 + sp;
    int e = FIRSTHALF ? s0 + sp : rp[i + 1];
    float a0 = 0, a1 = 0, a2 = 0, a3 = 0;
    if (FIRSTHALF && j == 0) {
        uint2 sv = *(const uint2*)(B + (size_t)i * 32 + q * 4);
        unpack2(sv.x, a0, a1); unpack2(sv.y, a2, a3);
    }
    for (int p = s + j; p < e; p += 8) {
        int nsrc = ci[p];
        uint2 v = *(const uint2*)(B + (size_t)nsrc * 32 + q * 4);
        float t0, t1;
        unpack2(v.x, t0, t1); a0 += t0; a1 += t1;
        unpack2(v.y, t0, t1); a2 += t0; a3 += t1;
    }
#pragma unroll
    for (int m = 8; m <= 32; m <<= 1) {
        a0 += __shfl_xor(a0, m); a1 += __shfl_xor(a1, m);
        a2 += __shfl_xor(a2, m); a3 += __shfl_xor(a3, m);
    }
    if (j == 0) {
        f16* zp = Z + (size_t)chunk * (MPAD * 32) + (size_t)i * 32 + q * 4;
        if (!FIRSTHALF) {
            uint2 zv = *(const uint2*)zp;
            float t0, t1;
            unpack2(zv.x, t0, t1); a0 += t0; a1 += t1;
            unpack2(zv.y, t0, t1); a2 += t0; a3 += t1;
        }
        uint2 o; o.x = pack2(a0, a1); o.y = pack2(a2, a3);
        *(uint2*)zp = o;
    }
}

// ---------------- GEMM: C[MPAD][256] = A[MPAD][K] @ Bt[256][K]^T ----------------
// ASTRIP: A element (node,k) at A[((k>>5)*MPAD + node)*32 + (k&31)]
// CSTRIP: C element (row,col) at C[((col>>5)*MPAD + row)*32 + (col&31)]
template <int K, bool RELU, bool ASTRIP, bool CSTRIP>
__global__ __launch_bounds__(256) void k_gemm(const f16* __restrict__ A,
                                              const f16* __restrict__ Bt,
                                              const float* __restrict__ bias,
                                              f16* __restrict__ C) {
    __shared__ f16 As[128 * 64];
    __shared__ f16 Bs[128 * 64];
    const int tid = threadIdx.x;
    const int bm0 = blockIdx.x * 128;
    const int bn0 = blockIdx.y * 128;
    const int lane = tid & 63, wave = tid >> 6;
    const int quad = lane >> 4, l16 = lane & 15;
    const int wr = (wave >> 1) * 64, wc = (wave & 1) * 64;
    f32x4 acc[4][4] = {};
    const f16* Abase = A + (size_t)bm0 * K;
    const f16* Bbase = Bt + (size_t)bn0 * K;

    for (int k0 = 0; k0 < K; k0 += 64) {
#pragma unroll
        for (int i = 0; i < 4; ++i) {
            int c = i * 256 + tid;
            int m = c >> 3;
            int gg = (c & 7) ^ (m & 7);
            int k = k0 + gg * 8;
            const f16* ga = ASTRIP
                ? A + ((size_t)(k >> 5) * MPAD + (bm0 + m)) * 32 + (k & 31)
                : Abase + (size_t)m * K + k;
            __builtin_amdgcn_global_load_lds(
                (const __attribute__((address_space(1))) unsigned int*)ga,
                (__attribute__((address_space(3))) unsigned int*)(As + (size_t)c * 8), 16, 0, 0);
            __builtin_amdgcn_global_load_lds(
                (const __attribute__((address_space(1))) unsigned int*)(Bbase + (size_t)m * K + k),
                (__attribute__((address_space(3))) unsigned int*)(Bs + (size_t)c * 8), 16, 0, 0);
        }
        __syncthreads();
#pragma unroll
        for (int kk = 0; kk < 64; kk += 32) {
            const int gbase = kk >> 3;
            f16x8 af[4], bfv[4];
#pragma unroll
            for (int mi = 0; mi < 4; ++mi) {
                int m = wr + mi * 16 + l16;
                int slot = (gbase + quad) ^ (m & 7);
                af[mi] = *(const f16x8*)&As[(m * 8 + slot) * 8];
            }
#pragma unroll
            for (int ni = 0; ni < 4; ++ni) {
                int m = wc + ni * 16 + l16;
                int slot = (gbase + quad) ^ (m & 7);
                bfv[ni] = *(const f16x8*)&Bs[(m * 8 + slot) * 8];
            }
#pragma unroll
            for (int mi = 0; mi < 4; ++mi)
#pragma unroll
                for (int ni = 0; ni < 4; ++ni)
                    acc[mi][ni] = __builtin_amdgcn_mfma_f32_16x16x32_f16(af[mi], bfv[ni], acc[mi][ni], 0, 0, 0);
        }
        __syncthreads();
    }

    float bv[4];
#pragma unroll
    for (int ni = 0; ni < 4; ++ni) bv[ni] = bias[bn0 + wc + ni * 16 + l16];
#pragma unroll
    for (int mi = 0; mi < 4; ++mi) {
#pragma unroll
        for (int r = 0; r < 4; ++r) {
            size_t row = (size_t)(bm0 + wr + mi * 16 + quad * 4 + r);
#pragma unroll
            for (int ni = 0; ni < 4; ++ni) {
                float v = acc[mi][ni][r] + bv[ni];
                if (RELU) v = fmaxf(v, 0.f);
                int col = bn0 + wc + ni * 16 + l16;
                if (CSTRIP)
                    C[((size_t)(col >> 5) * MPAD + row) * 32 + (col & 31)] = (f16)v;
                else
                    C[row * HID + col] = (f16)v;
            }
        }
    }
}

// ---------------- output head ----------------
__global__ void k_out(const uint2* __restrict__ h, const float* __restrict__ W,
                      const float* __restrict__ b, float* __restrict__ out, int n) {
    int gw = (blockIdx.x * 256 + threadIdx.x) >> 6;
    if (gw >= n) return;
    int lane = threadIdx.x & 63;
    uint2 d = h[(size_t)gw * 64 + lane];
    float x0, x1, x2, x3;
    unpack2(d.x, x0, x1); unpack2(d.y, x2, x3);
    int k = lane * 4;
    float o0 = x0 * W[k * 2 + 0] + x1 * W[k * 2 + 2] + x2 * W[k * 2 + 4] + x3 * W[k * 2 + 6];
    float o1 = x0 * W[k * 2 + 1] + x1 * W[k * 2 + 3] + x2 * W[k * 2 + 5] + x3 * W[k * 2 + 7];
#pragma unroll
    for (int off = 32; off > 0; off >>= 1) {
        o0 += __shfl_down(o0, off);
        o1 += __shfl_down(o1, off);
    }
    if (lane == 0) {
        out[(size_t)gw * 2 + 0] = o0 + b[0];
        out[(size_t)gw * 2 + 1] = o1 + b[1];
    }
}

extern "C" void kernel_launch(void* const* d_in, const int* in_sizes, int n_in,
                              void* d_out, int out_size, void* d_ws, size_t ws_size,
                              hipStream_t stream) {
    const float* x    = (const float*)d_in[0];
    const int*   ei   = (const int*)d_in[1];
    const int*   esrc = ei;
    const int*   edst = ei + N_EDGES;
    const float* lw[3][8];
    for (int l = 0; l < 3; ++l)
        for (int j = 0; j < 8; ++j) lw[l][j] = (const float*)d_in[2 + l * 8 + j];
    const float* outW = (const float*)d_in[26];
    const float* outB = (const float*)d_in[27];

    char* base = (char*)d_ws;
    size_t off = 0;
    auto alloc = [&](size_t bytes) -> void* {
        void* r = base + off;
        off += (bytes + 255) & ~(size_t)255;
        return r;
    };
    f16* zs = (f16*)alloc((size_t)8 * MPAD * 32 * 2);   // agg out, strips
    f16* y  = (f16*)alloc((size_t)MPAD * 256 * 2);      // after W1, normal
    f16* hs = (f16*)alloc((size_t)8 * MPAD * 32 * 2);   // layer out, strips
    f16* hn = (f16*)alloc((size_t)MPAD * 256 * 2);      // final layer out, normal
    f16* xh = (f16*)alloc((size_t)4 * MPAD * 32 * 2);   // x strips
    f16* W1t[3]; float* bias1[3]; f16* W2t[3];
    W1t[0] = (f16*)alloc(256 * 128 * 2);
    W1t[1] = (f16*)alloc(256 * 256 * 2);
    W1t[2] = (f16*)alloc(256 * 256 * 2);
    for (int l = 0; l < 3; ++l) W2t[l] = (f16*)alloc(256 * 256 * 2);
    for (int l = 0; l < 3; ++l) bias1[l] = (float*)alloc(256 * 4);
    unsigned* pairs = (unsigned*)alloc((size_t)NBUCK * BSTRIDE * 4);
    int* nb     = (int*)alloc(NBUCK * 4);
    int* bbase  = (int*)alloc(NBUCK * 4);
    int* rowptr = (int*)alloc((size_t)(N_NODES + 1) * 4);
    int* colidx = (int*)alloc((size_t)N_EDGES * 4);
    int* split  = (int*)alloc((size_t)N_NODES * 4);

    // CSR build + half-partition
    hipMemsetAsync(nb, 0, NBUCK * 4, stream);
    k_bucketA<<<(N_EDGES + 4095) / 4096, 256, 0, stream>>>(esrc, edst, pairs, nb, N_EDGES);
    k_scan196<<<1, 256, 0, stream>>>(nb, bbase, rowptr + N_NODES);
    k_bucketB<<<NBUCK, 256, 0, stream>>>(pairs, nb, bbase, rowptr, colidx);
    const int WBLOCKS = (N_NODES + 3) / 4;
    k_part<<<WBLOCKS, 256, 0, stream>>>(rowptr, colidx, split, N_NODES);

    // dtype prep
    k_cvt<<<(N_NODES * 64 + 255) / 256, 256, 0, stream>>>((const float2*)x, (unsigned*)xh, N_NODES * 64);
    k_foldw1<<<128, 256, 0, stream>>>(lw[0][0], lw[0][1], lw[0][2], lw[0][3], lw[0][4], lw[0][5], W1t[0], bias1[0], 128);
    k_foldw1<<<256, 256, 0, stream>>>(lw[1][0], lw[1][1], lw[1][2], lw[1][3], lw[1][4], lw[1][5], W1t[1], bias1[1], 256);
    k_foldw1<<<256, 256, 0, stream>>>(lw[2][0], lw[2][1], lw[2][2], lw[2][3], lw[2][4], lw[2][5], W1t[2], bias1[2], 256);
    for (int l = 0; l < 3; ++l)
        k_transb<<<256, 256, 0, stream>>>(lw[l][6], W2t[l]);

    const dim3 ggrid(MPAD / 128, 2);

    // layer 1
    k_aggs<4, true ><<<4 * NGRP, 1024, 0, stream>>>(xh, rowptr, colidx, split, zs);
    k_aggs<4, false><<<4 * NGRP, 1024, 0, stream>>>(xh, rowptr, colidx, split, zs);
    k_gemm<128, true, true,  false><<<ggrid, 256, 0, stream>>>(zs, W1t[0], bias1[0], y);
    k_gemm<256, true, false, true ><<<ggrid, 256, 0, stream>>>(y, W2t[0], lw[0][7], hs);
    // layer 2
    k_aggs<8, true ><<<8 * NGRP, 1024, 0, stream>>>(hs, rowptr, colidx, split, zs);
    k_aggs<8, false><<<8 * NGRP, 1024, 0, stream>>>(hs, rowptr, colidx, split, zs);
    k_gemm<256, true, true,  false><<<ggrid, 256, 0, stream>>>(zs, W1t[1], bias1[1], y);
    k_gemm<256, true, false, true ><<<ggrid, 256, 0, stream>>>(y, W2t[1], lw[1][7], hs);
    // layer 3
    k_aggs<8, true ><<<8 * NGRP, 1024, 0, stream>>>(hs, rowptr, colidx, split, zs);
    k_aggs<8, false><<<8 * NGRP, 1024, 0, stream>>>(hs, rowptr, colidx, split, zs);
    k_gemm<256, true, true,  false><<<ggrid, 256, 0, stream>>>(zs, W1t[2], bias1[2], y);
    k_gemm<256, false, false, false><<<ggrid, 256, 0, stream>>>(y, W2t[2], lw[2][7], hn);
    // output head
    k_out<<<WBLOCKS, 256, 0, stream>>>((const uint2*)hn, outW, outB, (float*)d_out, N_NODES);
}

// Round 6
// 969.330 us; speedup vs baseline: 1.9622x; 1.9622x over previous
//
#include <hip/hip_runtime.h>
#include <cstdint>
#include <cstddef>

#define N_NODES 100000
#define N_EDGES 3200000
#define MPAD    100096   // 782 * 128
#define HID     256
#define NBUCK   196
#define BSH     9
#define BSTRIDE 18432

typedef _Float16 f16;
typedef _Float16 f16x2 __attribute__((ext_vector_type(2)));
typedef _Float16 f16x8 __attribute__((ext_vector_type(8)));
typedef float    f32x4 __attribute__((ext_vector_type(4)));

union F16x2 { unsigned u; f16 h[2]; f16x2 v; };
__device__ inline void unpack2(unsigned u, float& a, float& b) {
    F16x2 x; x.u = u; a = (float)x.h[0]; b = (float)x.h[1];
}
__device__ inline unsigned pack2(float a, float b) {
    F16x2 x; x.h[0] = (f16)a; x.h[1] = (f16)b; return x.u;
}
__device__ inline f16x2 asv(unsigned u) { F16x2 x; x.u = u; return x.v; }

// ---------------- CSR build: bucketed counting sort ----------------
__global__ __launch_bounds__(256) void k_bucketA(const int* __restrict__ src,
                                                 const int* __restrict__ dst,
                                                 unsigned* __restrict__ pairs,
                                                 int* __restrict__ nb, int e) {
    __shared__ int hist[NBUCK];
    __shared__ int lbase[NBUCK];
    __shared__ int lcur[NBUCK];
    const int t = threadIdx.x;
    for (int i = t; i < NBUCK; i += 256) hist[i] = 0;
    __syncthreads();
    const int e0 = blockIdx.x * 4096;
    bool v[16]; int d[16], s[16];
#pragma unroll
    for (int i = 0; i < 16; ++i) {
        int idx = e0 + i * 256 + t;
        v[i] = idx < e;
        d[i] = v[i] ? dst[idx] : 0;
        s[i] = v[i] ? src[idx] : 0;
    }
#pragma unroll
    for (int i = 0; i < 16; ++i)
        if (v[i]) atomicAdd(&hist[d[i] >> BSH], 1);
    __syncthreads();
    for (int i = t; i < NBUCK; i += 256) {
        int h = hist[i];
        lbase[i] = h ? atomicAdd(&nb[i], h) : 0;
        lcur[i] = 0;
    }
    __syncthreads();
#pragma unroll
    for (int i = 0; i < 16; ++i) {
        if (v[i]) {
            int b = d[i] >> BSH;
            int p = atomicAdd(&lcur[b], 1);
            unsigned packed = ((unsigned)(d[i] & 511) << 17) | (unsigned)s[i];
            pairs[(size_t)b * BSTRIDE + lbase[b] + p] = packed;
        }
    }
}

__global__ void k_scan196(const int* __restrict__ nb, int* __restrict__ bbase,
                          int* __restrict__ rowptrN) {
    __shared__ int s[256];
    int t = threadIdx.x;
    int v = (t < NBUCK) ? nb[t] : 0;
    s[t] = v;
    __syncthreads();
    for (int off = 1; off < 256; off <<= 1) {
        int u = (t >= off) ? s[t - off] : 0;
        __syncthreads();
        s[t] += u;
        __syncthreads();
    }
    if (t < NBUCK) bbase[t] = s[t] - v;
    if (t == 0) *rowptrN = N_EDGES;
}

__global__ __launch_bounds__(256) void k_bucketB(const unsigned* __restrict__ pairs,
                                                 const int* __restrict__ nb,
                                                 const int* __restrict__ bbase,
                                                 int* __restrict__ rowptr,
                                                 int* __restrict__ colidx) {
    __shared__ int deg[512];
    __shared__ int sc[512];
    __shared__ int cur[512];
    const int b = blockIdx.x, t = threadIdx.x;
    const int cnt = nb[b], base = bbase[b];
    const unsigned* P = pairs + (size_t)b * BSTRIDE;
    deg[t] = 0; deg[t + 256] = 0;
    __syncthreads();
    for (int i = t; i < cnt; i += 256) atomicAdd(&deg[P[i] >> 17], 1);
    __syncthreads();
    sc[t] = deg[t]; sc[t + 256] = deg[t + 256];
    __syncthreads();
    for (int off = 1; off < 512; off <<= 1) {
        int a0 = (t >= off) ? sc[t - off] : 0;
        int a1 = (t + 256 >= off) ? sc[t + 256 - off] : 0;
        __syncthreads();
        sc[t] += a0; sc[t + 256] += a1;
        __syncthreads();
    }
    int node0 = b << BSH;
#pragma unroll
    for (int rep = 0; rep < 2; ++rep) {
        int i = t + rep * 256;
        int excl = base + sc[i] - deg[i];
        cur[i] = excl;
        int node = node0 + i;
        if (node < N_NODES) rowptr[node] = excl;
    }
    __syncthreads();
    for (int i = t; i < cnt; i += 256) {
        unsigned p = P[i];
        int pos = atomicAdd(&cur[p >> 17], 1);
        colidx[pos] = (int)(p & 0x1FFFF);
    }
}

// ---------------- dtype prep ----------------
__global__ void k_cvt(const float2* __restrict__ x, unsigned* __restrict__ o, int n) {
    int t = blockIdx.x * 256 + threadIdx.x;
    if (t < n) { float2 v = x[t]; o[t] = pack2(v.x, v.y); }
}

__global__ void k_foldw1(const float* __restrict__ W, const float* __restrict__ b1,
                         const float* __restrict__ gm, const float* __restrict__ bt,
                         const float* __restrict__ mu, const float* __restrict__ vr,
                         f16* __restrict__ Wt, float* __restrict__ bias, int K) {
    int t = blockIdx.x * 256 + threadIdx.x;
    if (t >= K * 256) return;
    int n = t & 255, k = t >> 8;
    float sc = gm[n] * rsqrtf(vr[n] + 1e-5f);
    Wt[n * K + k] = (f16)(W[t] * sc);
    if (k == 0) bias[n] = (b1[n] - mu[n]) * sc + bt[n];
}

__global__ void k_transb(const float* __restrict__ W, f16* __restrict__ Wt) {
    int t = blockIdx.x * 256 + threadIdx.x;
    int n = t & 255, k = t >> 8;
    Wt[n * 256 + k] = (f16)W[t];
}

// W2o[k][o] = sum_j W2[k][j]*outW[j][o]; bo[o] = sum_j b2[j]*outW[j][o] + outb[o]
__global__ void k_fold2(const float* __restrict__ W2, const float* __restrict__ b2,
                        const float* __restrict__ outW, const float* __restrict__ outb,
                        float* __restrict__ W2o, float* __restrict__ bo) {
    int k = threadIdx.x;
    float a0 = 0.f, a1 = 0.f;
    for (int j = 0; j < 256; ++j) {
        float w = W2[k * 256 + j];
        a0 += w * outW[j * 2 + 0];
        a1 += w * outW[j * 2 + 1];
    }
    W2o[k * 2 + 0] = a0;
    W2o[k * 2 + 1] = a1;
    if (k < 2) {
        float b = outb[k];
        for (int j = 0; j < 256; ++j) b += b2[j] * outW[j * 2 + k];
        bo[k] = b;
    }
}

// ---------------- aggregation: z = h + sum_{j->i} h_j ----------------
// 8-deep unroll; fp16 pairwise partial sums per 8-edge group, fp32 flush.
__global__ void k_agg256(const uint2* __restrict__ h, const int* __restrict__ rp,
                         const int* __restrict__ ci, uint2* __restrict__ z, int n) {
    int gw = (blockIdx.x * 256 + threadIdx.x) >> 6;
    if (gw >= n) return;
    int lane = threadIdx.x & 63;
    const uint2* hl = h + lane;
    uint2 d = hl[(size_t)gw * 64];
    float a0, a1, a2, a3, t0, t1;
    unpack2(d.x, a0, a1); unpack2(d.y, a2, a3);
    int s = rp[gw], e = rp[gw + 1];
    int p = s;
    for (; p + 7 < e; p += 8) {
        int j0 = ci[p],     j1 = ci[p + 1], j2 = ci[p + 2], j3 = ci[p + 3];
        int j4 = ci[p + 4], j5 = ci[p + 5], j6 = ci[p + 6], j7 = ci[p + 7];
        uint2 v0 = hl[(size_t)j0 * 64], v1 = hl[(size_t)j1 * 64];
        uint2 v2 = hl[(size_t)j2 * 64], v3 = hl[(size_t)j3 * 64];
        uint2 v4 = hl[(size_t)j4 * 64], v5 = hl[(size_t)j5 * 64];
        uint2 v6 = hl[(size_t)j6 * 64], v7 = hl[(size_t)j7 * 64];
        f16x2 sx = asv(v0.x), sy = asv(v0.y);
        sx += asv(v1.x); sy += asv(v1.y);
        sx += asv(v2.x); sy += asv(v2.y);
        sx += asv(v3.x); sy += asv(v3.y);
        sx += asv(v4.x); sy += asv(v4.y);
        sx += asv(v5.x); sy += asv(v5.y);
        sx += asv(v6.x); sy += asv(v6.y);
        sx += asv(v7.x); sy += asv(v7.y);
        a0 += (float)sx[0]; a1 += (float)sx[1];
        a2 += (float)sy[0]; a3 += (float)sy[1];
    }
    for (; p < e; ++p) {
        uint2 v0 = hl[(size_t)ci[p] * 64];
        unpack2(v0.x, t0, t1); a0 += t0; a1 += t1;
        unpack2(v0.y, t0, t1); a2 += t0; a3 += t1;
    }
    uint2 o; o.x = pack2(a0, a1); o.y = pack2(a2, a3);
    z[(size_t)gw * 64 + lane] = o;
}

__global__ void k_agg128(const unsigned* __restrict__ h, const int* __restrict__ rp,
                         const int* __restrict__ ci, unsigned* __restrict__ z, int n) {
    int gw = (blockIdx.x * 256 + threadIdx.x) >> 6;
    if (gw >= n) return;
    int lane = threadIdx.x & 63;
    const unsigned* hl = h + lane;
    float a0, a1, t0, t1;
    unpack2(hl[(size_t)gw * 64], a0, a1);
    int s = rp[gw], e = rp[gw + 1];
    int p = s;
    for (; p + 7 < e; p += 8) {
        int j0 = ci[p],     j1 = ci[p + 1], j2 = ci[p + 2], j3 = ci[p + 3];
        int j4 = ci[p + 4], j5 = ci[p + 5], j6 = ci[p + 6], j7 = ci[p + 7];
        unsigned v0 = hl[(size_t)j0 * 64], v1 = hl[(size_t)j1 * 64];
        unsigned v2 = hl[(size_t)j2 * 64], v3 = hl[(size_t)j3 * 64];
        unsigned v4 = hl[(size_t)j4 * 64], v5 = hl[(size_t)j5 * 64];
        unsigned v6 = hl[(size_t)j6 * 64], v7 = hl[(size_t)j7 * 64];
        f16x2 sx = asv(v0);
        sx += asv(v1); sx += asv(v2); sx += asv(v3);
        sx += asv(v4); sx += asv(v5); sx += asv(v6); sx += asv(v7);
        a0 += (float)sx[0]; a1 += (float)sx[1];
    }
    for (; p < e; ++p) {
        unpack2(hl[(size_t)ci[p] * 64], t0, t1); a0 += t0; a1 += t1;
    }
    z[(size_t)gw * 64 + lane] = pack2(a0, a1);
}

// ---------------- GEMM: C[MPAD][256] = A[MPAD][K] @ Bt[256][K]^T (+bias, relu) ----------------
template <int K, bool RELU>
__global__ __launch_bounds__(256) void k_gemm(const f16* __restrict__ A,
                                              const f16* __restrict__ Bt,
                                              const float* __restrict__ bias,
                                              f16* __restrict__ C) {
    __shared__ f16 As[128 * 64];
    __shared__ f16 Bs[128 * 64];
    const int tid = threadIdx.x;
    const int bm0 = blockIdx.x * 128;
    const int bn0 = blockIdx.y * 128;
    const int lane = tid & 63, wave = tid >> 6;
    const int quad = lane >> 4, l16 = lane & 15;
    const int wr = (wave >> 1) * 64, wc = (wave & 1) * 64;
    f32x4 acc[4][4] = {};
    const f16* Abase = A + (size_t)bm0 * K;
    const f16* Bbase = Bt + (size_t)bn0 * K;

    for (int k0 = 0; k0 < K; k0 += 64) {
#pragma unroll
        for (int i = 0; i < 4; ++i) {
            int c = i * 256 + tid;
            int m = c >> 3;
            int gg = (c & 7) ^ (m & 7);
            __builtin_amdgcn_global_load_lds(
                (const __attribute__((address_space(1))) unsigned int*)(Abase + (size_t)m * K + k0 + gg * 8),
                (__attribute__((address_space(3))) unsigned int*)(As + (size_t)c * 8), 16, 0, 0);
            __builtin_amdgcn_global_load_lds(
                (const __attribute__((address_space(1))) unsigned int*)(Bbase + (size_t)m * K + k0 + gg * 8),
                (__attribute__((address_space(3))) unsigned int*)(Bs + (size_t)c * 8), 16, 0, 0);
        }
        __syncthreads();
#pragma unroll
        for (int kk = 0; kk < 64; kk += 32) {
            const int gbase = kk >> 3;
            f16x8 af[4], bfv[4];
#pragma unroll
            for (int mi = 0; mi < 4; ++mi) {
                int m = wr + mi * 16 + l16;
                int slot = (gbase + quad) ^ (m & 7);
                af[mi] = *(const f16x8*)&As[(m * 8 + slot) * 8];
            }
#pragma unroll
            for (int ni = 0; ni < 4; ++ni) {
                int m = wc + ni * 16 + l16;
                int slot = (gbase + quad) ^ (m & 7);
                bfv[ni] = *(const f16x8*)&Bs[(m * 8 + slot) * 8];
            }
#pragma unroll
            for (int mi = 0; mi < 4; ++mi)
#pragma unroll
                for (int ni = 0; ni < 4; ++ni)
                    acc[mi][ni] = __builtin_amdgcn_mfma_f32_16x16x32_f16(af[mi], bfv[ni], acc[mi][ni], 0, 0, 0);
        }
        __syncthreads();
    }

    float bv[4];
#pragma unroll
    for (int ni = 0; ni < 4; ++ni) bv[ni] = bias[bn0 + wc + ni * 16 + l16];
#pragma unroll
    for (int mi = 0; mi < 4; ++mi) {
#pragma unroll
        for (int r = 0; r < 4; ++r) {
            size_t row = (size_t)(bm0 + wr + mi * 16 + quad * 4 + r);
            f16* crow = C + row * HID + bn0 + wc + l16;
#pragma unroll
            for (int ni = 0; ni < 4; ++ni) {
                float v = acc[mi][ni][r] + bv[ni];
                if (RELU) v = fmaxf(v, 0.f);
                crow[ni * 16] = (f16)v;
            }
        }
    }
}

// ---------------- head: out[N][2] = y[N][256] @ W2o[256][2] + bo ----------------
__global__ void k_head(const uint2* __restrict__ y, const float* __restrict__ W2o,
                       const float* __restrict__ bo, float* __restrict__ out, int n) {
    __shared__ float w[512];
    __shared__ float bb[2];
    int t = threadIdx.x;
    w[t] = W2o[t];            // 256-thread block: load both halves
    w[t + 256] = W2o[t + 256];
    if (t < 2) bb[t] = bo[t];
    __syncthreads();
    int gw = (blockIdx.x * 256 + t) >> 6;
    if (gw >= n) return;
    int lane = t & 63;
    uint2 d = y[(size_t)gw * 64 + lane];
    float x0, x1, x2, x3;
    unpack2(d.x, x0, x1); unpack2(d.y, x2, x3);
    int k = lane * 4;
    float o0 = x0 * w[k * 2 + 0] + x1 * w[k * 2 + 2] + x2 * w[k * 2 + 4] + x3 * w[k * 2 + 6];
    float o1 = x0 * w[k * 2 + 1] + x1 * w[k * 2 + 3] + x2 * w[k * 2 + 5] + x3 * w[k * 2 + 7];
#pragma unroll
    for (int off = 32; off > 0; off >>= 1) {
        o0 += __shfl_down(o0, off);
        o1 += __shfl_down(o1, off);
    }
    if (lane == 0) {
        out[(size_t)gw * 2 + 0] = o0 + bb[0];
        out[(size_t)gw * 2 + 1] = o1 + bb[1];
    }
}

extern "C" void kernel_launch(void* const* d_in, const int* in_sizes, int n_in,
                              void* d_out, int out_size, void* d_ws, size_t ws_size,
                              hipStream_t stream) {
    const float* x    = (const float*)d_in[0];
    const int*   ei   = (const int*)d_in[1];
    const int*   esrc = ei;
    const int*   edst = ei + N_EDGES;
    const float* lw[3][8];
    for (int l = 0; l < 3; ++l)
        for (int j = 0; j < 8; ++j) lw[l][j] = (const float*)d_in[2 + l * 8 + j];
    const float* outW = (const float*)d_in[26];
    const float* outB = (const float*)d_in[27];

    char* base = (char*)d_ws;
    size_t off = 0;
    auto alloc = [&](size_t bytes) -> void* {
        void* r = base + off;
        off += (bytes + 255) & ~(size_t)255;
        return r;
    };
    f16* z  = (f16*)alloc((size_t)MPAD * 256 * 2);
    f16* y  = (f16*)alloc((size_t)MPAD * 256 * 2);
    f16* h  = (f16*)alloc((size_t)MPAD * 256 * 2);
    f16* xh = (f16*)alloc((size_t)MPAD * 128 * 2);
    f16* W1t[3]; float* bias1[3]; f16* W2t[2];
    W1t[0] = (f16*)alloc(256 * 128 * 2);
    W1t[1] = (f16*)alloc(256 * 256 * 2);
    W1t[2] = (f16*)alloc(256 * 256 * 2);
    for (int l = 0; l < 2; ++l) W2t[l] = (f16*)alloc(256 * 256 * 2);
    for (int l = 0; l < 3; ++l) bias1[l] = (float*)alloc(256 * 4);
    float* W2o = (float*)alloc(512 * 4);
    float* bo  = (float*)alloc(2 * 4);
    unsigned* pairs = (unsigned*)alloc((size_t)NBUCK * BSTRIDE * 4);
    int* nb     = (int*)alloc(NBUCK * 4);
    int* bbase  = (int*)alloc(NBUCK * 4);
    int* rowptr = (int*)alloc((size_t)(N_NODES + 1) * 4);
    int* colidx = (int*)alloc((size_t)N_EDGES * 4);

    // CSR build
    hipMemsetAsync(nb, 0, NBUCK * 4, stream);
    k_bucketA<<<(N_EDGES + 4095) / 4096, 256, 0, stream>>>(esrc, edst, pairs, nb, N_EDGES);
    k_scan196<<<1, 256, 0, stream>>>(nb, bbase, rowptr + N_NODES);
    k_bucketB<<<NBUCK, 256, 0, stream>>>(pairs, nb, bbase, rowptr, colidx);

    // dtype prep + weight folds
    k_cvt<<<(N_NODES * 64 + 255) / 256, 256, 0, stream>>>((const float2*)x, (unsigned*)xh, N_NODES * 64);
    k_foldw1<<<128, 256, 0, stream>>>(lw[0][0], lw[0][1], lw[0][2], lw[0][3], lw[0][4], lw[0][5], W1t[0], bias1[0], 128);
    k_foldw1<<<256, 256, 0, stream>>>(lw[1][0], lw[1][1], lw[1][2], lw[1][3], lw[1][4], lw[1][5], W1t[1], bias1[1], 256);
    k_foldw1<<<256, 256, 0, stream>>>(lw[2][0], lw[2][1], lw[2][2], lw[2][3], lw[2][4], lw[2][5], W1t[2], bias1[2], 256);
    k_transb<<<256, 256, 0, stream>>>(lw[0][6], W2t[0]);
    k_transb<<<256, 256, 0, stream>>>(lw[1][6], W2t[1]);
    k_fold2<<<1, 256, 0, stream>>>(lw[2][6], lw[2][7], outW, outB, W2o, bo);

    const dim3 ggrid(MPAD / 128, 2);
    const int WBLOCKS = (N_NODES + 3) / 4;

    // layer 1
    k_agg128<<<WBLOCKS, 256, 0, stream>>>((const unsigned*)xh, rowptr, colidx, (unsigned*)z, N_NODES);
    k_gemm<128, true><<<ggrid, 256, 0, stream>>>(z, W1t[0], bias1[0], y);
    k_gemm<256, true><<<ggrid, 256, 0, stream>>>(y, W2t[0], lw[0][7], h);
    // layer 2
    k_agg256<<<WBLOCKS, 256, 0, stream>>>((const uint2*)h, rowptr, colidx, (uint2*)z, N_NODES);
    k_gemm<256, true><<<ggrid, 256, 0, stream>>>(z, W1t[1], bias1[1], y);
    k_gemm<256, true><<<ggrid, 256, 0, stream>>>(y, W2t[1], lw[1][7], h);
    // layer 3: GEMM1 only; W2 folded with output head
    k_agg256<<<WBLOCKS, 256, 0, stream>>>((const uint2*)h, rowptr, colidx, (uint2*)z, N_NODES);
    k_gemm<256, true><<<ggrid, 256, 0, stream>>>(z, W1t[2], bias1[2], y);
    // head
    k_head<<<WBLOCKS, 256, 0, stream>>>((const uint2*)y, W2o, bo, (float*)d_out, N_NODES);
}

// Round 7
// 789.079 us; speedup vs baseline: 2.4104x; 1.2284x over previous
//
#include <hip/hip_runtime.h>
#include <cstdint>
#include <cstddef>

#define N_NODES 100000
#define N_EDGES 3200000
#define MPAD    100096   // 782 * 128
#define HID     256
#define NBUCK   196
#define BSH     9
#define BSTRIDE 18432

typedef _Float16 f16;
typedef _Float16 f16x2 __attribute__((ext_vector_type(2)));
typedef _Float16 f16x8 __attribute__((ext_vector_type(8)));
typedef float    f32x4 __attribute__((ext_vector_type(4)));

union F16x2 { unsigned u; f16 h[2]; f16x2 v; };
__device__ inline void unpack2(unsigned u, float& a, float& b) {
    F16x2 x; x.u = u; a = (float)x.h[0]; b = (float)x.h[1];
}
__device__ inline unsigned pack2(float a, float b) {
    F16x2 x; x.h[0] = (f16)a; x.h[1] = (f16)b; return x.u;
}
__device__ inline f16x2 asv(unsigned u) { F16x2 x; x.u = u; return x.v; }

// ---------------- CSR build: bucketed counting sort ----------------
__global__ __launch_bounds__(256) void k_bucketA(const int* __restrict__ src,
                                                 const int* __restrict__ dst,
                                                 unsigned* __restrict__ pairs,
                                                 int* __restrict__ nb, int e) {
    __shared__ int hist[NBUCK];
    __shared__ int lbase[NBUCK];
    __shared__ int lcur[NBUCK];
    const int t = threadIdx.x;
    for (int i = t; i < NBUCK; i += 256) hist[i] = 0;
    __syncthreads();
    const int e0 = blockIdx.x * 4096;
    bool v[16]; int d[16], s[16];
#pragma unroll
    for (int i = 0; i < 16; ++i) {
        int idx = e0 + i * 256 + t;
        v[i] = idx < e;
        d[i] = v[i] ? dst[idx] : 0;
        s[i] = v[i] ? src[idx] : 0;
    }
#pragma unroll
    for (int i = 0; i < 16; ++i)
        if (v[i]) atomicAdd(&hist[d[i] >> BSH], 1);
    __syncthreads();
    for (int i = t; i < NBUCK; i += 256) {
        int h = hist[i];
        lbase[i] = h ? atomicAdd(&nb[i], h) : 0;
        lcur[i] = 0;
    }
    __syncthreads();
#pragma unroll
    for (int i = 0; i < 16; ++i) {
        if (v[i]) {
            int b = d[i] >> BSH;
            int p = atomicAdd(&lcur[b], 1);
            unsigned packed = ((unsigned)(d[i] & 511) << 17) | (unsigned)s[i];
            pairs[(size_t)b * BSTRIDE + lbase[b] + p] = packed;
        }
    }
}

__global__ void k_scan196(const int* __restrict__ nb, int* __restrict__ bbase,
                          int* __restrict__ rowptrN) {
    __shared__ int s[256];
    int t = threadIdx.x;
    int v = (t < NBUCK) ? nb[t] : 0;
    s[t] = v;
    __syncthreads();
    for (int off = 1; off < 256; off <<= 1) {
        int u = (t >= off) ? s[t - off] : 0;
        __syncthreads();
        s[t] += u;
        __syncthreads();
    }
    if (t < NBUCK) bbase[t] = s[t] - v;
    if (t == 0) *rowptrN = N_EDGES;
}

__global__ __launch_bounds__(256) void k_bucketB(const unsigned* __restrict__ pairs,
                                                 const int* __restrict__ nb,
                                                 const int* __restrict__ bbase,
                                                 int* __restrict__ rowptr,
                                                 int* __restrict__ colidx) {
    __shared__ int deg[512];
    __shared__ int sc[512];
    __shared__ int cur[512];
    const int b = blockIdx.x, t = threadIdx.x;
    const int cnt = nb[b], base = bbase[b];
    const unsigned* P = pairs + (size_t)b * BSTRIDE;
    deg[t] = 0; deg[t + 256] = 0;
    __syncthreads();
    for (int i = t; i < cnt; i += 256) atomicAdd(&deg[P[i] >> 17], 1);
    __syncthreads();
    sc[t] = deg[t]; sc[t + 256] = deg[t + 256];
    __syncthreads();
    for (int off = 1; off < 512; off <<= 1) {
        int a0 = (t >= off) ? sc[t - off] : 0;
        int a1 = (t + 256 >= off) ? sc[t + 256 - off] : 0;
        __syncthreads();
        sc[t] += a0; sc[t + 256] += a1;
        __syncthreads();
    }
    int node0 = b << BSH;
#pragma unroll
    for (int rep = 0; rep < 2; ++rep) {
        int i = t + rep * 256;
        int excl = base + sc[i] - deg[i];
        cur[i] = excl;
        int node = node0 + i;
        if (node < N_NODES) rowptr[node] = excl;
    }
    __syncthreads();
    for (int i = t; i < cnt; i += 256) {
        unsigned p = P[i];
        int pos = atomicAdd(&cur[p >> 17], 1);
        colidx[pos] = (int)(p & 0x1FFFF);
    }
}

// ---------------- dtype prep ----------------
__global__ void k_cvt(const float2* __restrict__ x, unsigned* __restrict__ o, int n) {
    int t = blockIdx.x * 256 + threadIdx.x;
    if (t < n) { float2 v = x[t]; o[t] = pack2(v.x, v.y); }
}

__global__ void k_foldw1(const float* __restrict__ W, const float* __restrict__ b1,
                         const float* __restrict__ gm, const float* __restrict__ bt,
                         const float* __restrict__ mu, const float* __restrict__ vr,
                         f16* __restrict__ Wt, float* __restrict__ bias, int K) {
    int t = blockIdx.x * 256 + threadIdx.x;
    if (t >= K * 256) return;
    int n = t & 255, k = t >> 8;
    float sc = gm[n] * rsqrtf(vr[n] + 1e-5f);
    Wt[n * K + k] = (f16)(W[t] * sc);
    if (k == 0) bias[n] = (b1[n] - mu[n]) * sc + bt[n];
}

__global__ void k_transb(const float* __restrict__ W, f16* __restrict__ Wt) {
    int t = blockIdx.x * 256 + threadIdx.x;
    int n = t & 255, k = t >> 8;
    Wt[n * 256 + k] = (f16)W[t];
}

// W2o[k][o] = sum_j W2[k][j]*outW[j][o]; bo[o] = sum_j b2[j]*outW[j][o] + outb[o]
__global__ void k_fold2(const float* __restrict__ W2, const float* __restrict__ b2,
                        const float* __restrict__ outW, const float* __restrict__ outb,
                        float* __restrict__ W2o, float* __restrict__ bo) {
    int k = threadIdx.x;
    float a0 = 0.f, a1 = 0.f;
    for (int j = 0; j < 256; ++j) {
        float w = W2[k * 256 + j];
        a0 += w * outW[j * 2 + 0];
        a1 += w * outW[j * 2 + 1];
    }
    W2o[k * 2 + 0] = a0;
    W2o[k * 2 + 1] = a1;
    if (k < 2) {
        float b = outb[k];
        for (int j = 0; j < 256; ++j) b += b2[j] * outW[j * 2 + k];
        bo[k] = b;
    }
}

// ---------------- aggregation ----------------
// z = h + sum_{j->i} h_j. Self term fp16; neighbor gathers read the fp8 e4m3
// table h8 (256 B/row -> half the L2-miss fill traffic). fp32 accumulate.
__global__ void k_agg256(const uint2* __restrict__ h, const unsigned* __restrict__ h8,
                         const int* __restrict__ rp, const int* __restrict__ ci,
                         uint2* __restrict__ z, int n) {
    int gw = (blockIdx.x * 256 + threadIdx.x) >> 6;
    if (gw >= n) return;
    int lane = threadIdx.x & 63;
    const unsigned* h8l = h8 + lane;   // lane's 4-byte slot of each 256 B row
    uint2 d = h[(size_t)gw * 64 + lane];
    float a0, a1, a2, a3;
    unpack2(d.x, a0, a1); unpack2(d.y, a2, a3);
    int s = rp[gw], e = rp[gw + 1];
    int p = s;
    for (; p + 7 < e; p += 8) {
        int j0 = ci[p],     j1 = ci[p + 1], j2 = ci[p + 2], j3 = ci[p + 3];
        int j4 = ci[p + 4], j5 = ci[p + 5], j6 = ci[p + 6], j7 = ci[p + 7];
        unsigned u0 = h8l[(size_t)j0 * 64], u1 = h8l[(size_t)j1 * 64];
        unsigned u2 = h8l[(size_t)j2 * 64], u3 = h8l[(size_t)j3 * 64];
        unsigned u4 = h8l[(size_t)j4 * 64], u5 = h8l[(size_t)j5 * 64];
        unsigned u6 = h8l[(size_t)j6 * 64], u7 = h8l[(size_t)j7 * 64];
#pragma unroll
        for (int q = 0; q < 8; ++q) {
            unsigned u = q == 0 ? u0 : q == 1 ? u1 : q == 2 ? u2 : q == 3 ? u3
                       : q == 4 ? u4 : q == 5 ? u5 : q == 6 ? u6 : u7;
            auto lo = __builtin_amdgcn_cvt_pk_f32_fp8(u, false);
            auto hi = __builtin_amdgcn_cvt_pk_f32_fp8(u, true);
            a0 += lo[0]; a1 += lo[1]; a2 += hi[0]; a3 += hi[1];
        }
    }
    for (; p < e; ++p) {
        unsigned u = h8l[(size_t)ci[p] * 64];
        auto lo = __builtin_amdgcn_cvt_pk_f32_fp8(u, false);
        auto hi = __builtin_amdgcn_cvt_pk_f32_fp8(u, true);
        a0 += lo[0]; a1 += lo[1]; a2 += hi[0]; a3 += hi[1];
    }
    uint2 o; o.x = pack2(a0, a1); o.y = pack2(a2, a3);
    z[(size_t)gw * 64 + lane] = o;
}

// layer-1: x stays fp16 (signed values -> cancellation would amplify fp8 error)
__global__ void k_agg128(const unsigned* __restrict__ h, const int* __restrict__ rp,
                         const int* __restrict__ ci, unsigned* __restrict__ z, int n) {
    int gw = (blockIdx.x * 256 + threadIdx.x) >> 6;
    if (gw >= n) return;
    int lane = threadIdx.x & 63;
    const unsigned* hl = h + lane;
    float a0, a1, t0, t1;
    unpack2(hl[(size_t)gw * 64], a0, a1);
    int s = rp[gw], e = rp[gw + 1];
    int p = s;
    for (; p + 7 < e; p += 8) {
        int j0 = ci[p],     j1 = ci[p + 1], j2 = ci[p + 2], j3 = ci[p + 3];
        int j4 = ci[p + 4], j5 = ci[p + 5], j6 = ci[p + 6], j7 = ci[p + 7];
        unsigned v0 = hl[(size_t)j0 * 64], v1 = hl[(size_t)j1 * 64];
        unsigned v2 = hl[(size_t)j2 * 64], v3 = hl[(size_t)j3 * 64];
        unsigned v4 = hl[(size_t)j4 * 64], v5 = hl[(size_t)j5 * 64];
        unsigned v6 = hl[(size_t)j6 * 64], v7 = hl[(size_t)j7 * 64];
        f16x2 sx = asv(v0);
        sx += asv(v1); sx += asv(v2); sx += asv(v3);
        sx += asv(v4); sx += asv(v5); sx += asv(v6); sx += asv(v7);
        a0 += (float)sx[0]; a1 += (float)sx[1];
    }
    for (; p < e; ++p) {
        unpack2(hl[(size_t)ci[p] * 64], t0, t1); a0 += t0; a1 += t1;
    }
    z[(size_t)gw * 64 + lane] = pack2(a0, a1);
}

// ---------------- GEMM: C[MPAD][256] = A[MPAD][K] @ Bt[256][K]^T (+bias, relu) ----------------
// STORE8: also emit fp8 e4m3 copy C8 (gather table for the next agg stage)
template <int K, bool RELU, bool STORE8>
__global__ __launch_bounds__(256) void k_gemm(const f16* __restrict__ A,
                                              const f16* __restrict__ Bt,
                                              const float* __restrict__ bias,
                                              f16* __restrict__ C,
                                              unsigned char* __restrict__ C8) {
    __shared__ f16 As[128 * 64];
    __shared__ f16 Bs[128 * 64];
    const int tid = threadIdx.x;
    const int bm0 = blockIdx.x * 128;
    const int bn0 = blockIdx.y * 128;
    const int lane = tid & 63, wave = tid >> 6;
    const int quad = lane >> 4, l16 = lane & 15;
    const int wr = (wave >> 1) * 64, wc = (wave & 1) * 64;
    f32x4 acc[4][4] = {};
    const f16* Abase = A + (size_t)bm0 * K;
    const f16* Bbase = Bt + (size_t)bn0 * K;

    for (int k0 = 0; k0 < K; k0 += 64) {
#pragma unroll
        for (int i = 0; i < 4; ++i) {
            int c = i * 256 + tid;
            int m = c >> 3;
            int gg = (c & 7) ^ (m & 7);
            __builtin_amdgcn_global_load_lds(
                (const __attribute__((address_space(1))) unsigned int*)(Abase + (size_t)m * K + k0 + gg * 8),
                (__attribute__((address_space(3))) unsigned int*)(As + (size_t)c * 8), 16, 0, 0);
            __builtin_amdgcn_global_load_lds(
                (const __attribute__((address_space(1))) unsigned int*)(Bbase + (size_t)m * K + k0 + gg * 8),
                (__attribute__((address_space(3))) unsigned int*)(Bs + (size_t)c * 8), 16, 0, 0);
        }
        __syncthreads();
#pragma unroll
        for (int kk = 0; kk < 64; kk += 32) {
            const int gbase = kk >> 3;
            f16x8 af[4], bfv[4];
#pragma unroll
            for (int mi = 0; mi < 4; ++mi) {
                int m = wr + mi * 16 + l16;
                int slot = (gbase + quad) ^ (m & 7);
                af[mi] = *(const f16x8*)&As[(m * 8 + slot) * 8];
            }
#pragma unroll
            for (int ni = 0; ni < 4; ++ni) {
                int m = wc + ni * 16 + l16;
                int slot = (gbase + quad) ^ (m & 7);
                bfv[ni] = *(const f16x8*)&Bs[(m * 8 + slot) * 8];
            }
#pragma unroll
            for (int mi = 0; mi < 4; ++mi)
#pragma unroll
                for (int ni = 0; ni < 4; ++ni)
                    acc[mi][ni] = __builtin_amdgcn_mfma_f32_16x16x32_f16(af[mi], bfv[ni], acc[mi][ni], 0, 0, 0);
        }
        __syncthreads();
    }

    float bv[4];
#pragma unroll
    for (int ni = 0; ni < 4; ++ni) bv[ni] = bias[bn0 + wc + ni * 16 + l16];
#pragma unroll
    for (int mi = 0; mi < 4; ++mi) {
#pragma unroll
        for (int r = 0; r < 4; ++r) {
            size_t row = (size_t)(bm0 + wr + mi * 16 + quad * 4 + r);
            f16* crow = C + row * HID + bn0 + wc + l16;
            unsigned char* crow8 = STORE8 ? (C8 + row * HID + bn0 + wc + l16) : nullptr;
#pragma unroll
            for (int ni = 0; ni < 4; ++ni) {
                float v = acc[mi][ni][r] + bv[ni];
                if (RELU) v = fmaxf(v, 0.f);
                crow[ni * 16] = (f16)v;
                if (STORE8) {
                    int pk = __builtin_amdgcn_cvt_pk_fp8_f32(v, v, 0, false);
                    crow8[ni * 16] = (unsigned char)(pk & 0xff);
                }
            }
        }
    }
}

// ---------------- head: out[N][2] = y[N][256] @ W2o[256][2] + bo ----------------
__global__ void k_head(const uint2* __restrict__ y, const float* __restrict__ W2o,
                       const float* __restrict__ bo, float* __restrict__ out, int n) {
    __shared__ float w[512];
    __shared__ float bb[2];
    int t = threadIdx.x;
    w[t] = W2o[t];
    w[t + 256] = W2o[t + 256];
    if (t < 2) bb[t] = bo[t];
    __syncthreads();
    int gw = (blockIdx.x * 256 + t) >> 6;
    if (gw >= n) return;
    int lane = t & 63;
    uint2 d = y[(size_t)gw * 64 + lane];
    float x0, x1, x2, x3;
    unpack2(d.x, x0, x1); unpack2(d.y, x2, x3);
    int k = lane * 4;
    float o0 = x0 * w[k * 2 + 0] + x1 * w[k * 2 + 2] + x2 * w[k * 2 + 4] + x3 * w[k * 2 + 6];
    float o1 = x0 * w[k * 2 + 1] + x1 * w[k * 2 + 3] + x2 * w[k * 2 + 5] + x3 * w[k * 2 + 7];
#pragma unroll
    for (int off = 32; off > 0; off >>= 1) {
        o0 += __shfl_down(o0, off);
        o1 += __shfl_down(o1, off);
    }
    if (lane == 0) {
        out[(size_t)gw * 2 + 0] = o0 + bb[0];
        out[(size_t)gw * 2 + 1] = o1 + bb[1];
    }
}

extern "C" void kernel_launch(void* const* d_in, const int* in_sizes, int n_in,
                              void* d_out, int out_size, void* d_ws, size_t ws_size,
                              hipStream_t stream) {
    const float* x    = (const float*)d_in[0];
    const int*   ei   = (const int*)d_in[1];
    const int*   esrc = ei;
    const int*   edst = ei + N_EDGES;
    const float* lw[3][8];
    for (int l = 0; l < 3; ++l)
        for (int j = 0; j < 8; ++j) lw[l][j] = (const float*)d_in[2 + l * 8 + j];
    const float* outW = (const float*)d_in[26];
    const float* outB = (const float*)d_in[27];

    char* base = (char*)d_ws;
    size_t off = 0;
    auto alloc = [&](size_t bytes) -> void* {
        void* r = base + off;
        off += (bytes + 255) & ~(size_t)255;
        return r;
    };
    f16* z  = (f16*)alloc((size_t)MPAD * 256 * 2);
    f16* y  = (f16*)alloc((size_t)MPAD * 256 * 2);
    f16* h  = (f16*)alloc((size_t)MPAD * 256 * 2);
    unsigned char* h8 = (unsigned char*)alloc((size_t)MPAD * 256);
    f16* xh = (f16*)alloc((size_t)MPAD * 128 * 2);
    f16* W1t[3]; float* bias1[3]; f16* W2t[2];
    W1t[0] = (f16*)alloc(256 * 128 * 2);
    W1t[1] = (f16*)alloc(256 * 256 * 2);
    W1t[2] = (f16*)alloc(256 * 256 * 2);
    for (int l = 0; l < 2; ++l) W2t[l] = (f16*)alloc(256 * 256 * 2);
    for (int l = 0; l < 3; ++l) bias1[l] = (float*)alloc(256 * 4);
    float* W2o = (float*)alloc(512 * 4);
    float* bo  = (float*)alloc(2 * 4);
    unsigned* pairs = (unsigned*)alloc((size_t)NBUCK * BSTRIDE * 4);
    int* nb     = (int*)alloc(NBUCK * 4);
    int* bbase  = (int*)alloc(NBUCK * 4);
    int* rowptr = (int*)alloc((size_t)(N_NODES + 1) * 4);
    int* colidx = (int*)alloc((size_t)N_EDGES * 4);

    // CSR build
    hipMemsetAsync(nb, 0, NBUCK * 4, stream);
    k_bucketA<<<(N_EDGES + 4095) / 4096, 256, 0, stream>>>(esrc, edst, pairs, nb, N_EDGES);
    k_scan196<<<1, 256, 0, stream>>>(nb, bbase, rowptr + N_NODES);
    k_bucketB<<<NBUCK, 256, 0, stream>>>(pairs, nb, bbase, rowptr, colidx);

    // dtype prep + weight folds
    k_cvt<<<(N_NODES * 64 + 255) / 256, 256, 0, stream>>>((const float2*)x, (unsigned*)xh, N_NODES * 64);
    k_foldw1<<<128, 256, 0, stream>>>(lw[0][0], lw[0][1], lw[0][2], lw[0][3], lw[0][4], lw[0][5], W1t[0], bias1[0], 128);
    k_foldw1<<<256, 256, 0, stream>>>(lw[1][0], lw[1][1], lw[1][2], lw[1][3], lw[1][4], lw[1][5], W1t[1], bias1[1], 256);
    k_foldw1<<<256, 256, 0, stream>>>(lw[2][0], lw[2][1], lw[2][2], lw[2][3], lw[2][4], lw[2][5], W1t[2], bias1[2], 256);
    k_transb<<<256, 256, 0, stream>>>(lw[0][6], W2t[0]);
    k_transb<<<256, 256, 0, stream>>>(lw[1][6], W2t[1]);
    k_fold2<<<1, 256, 0, stream>>>(lw[2][6], lw[2][7], outW, outB, W2o, bo);

    const dim3 ggrid(MPAD / 128, 2);
    const int WBLOCKS = (N_NODES + 3) / 4;

    // layer 1
    k_agg128<<<WBLOCKS, 256, 0, stream>>>((const unsigned*)xh, rowptr, colidx, (unsigned*)z, N_NODES);
    k_gemm<128, true, false><<<ggrid, 256, 0, stream>>>(z, W1t[0], bias1[0], y, nullptr);
    k_gemm<256, true, true ><<<ggrid, 256, 0, stream>>>(y, W2t[0], lw[0][7], h, h8);
    // layer 2
    k_agg256<<<WBLOCKS, 256, 0, stream>>>((const uint2*)h, (const unsigned*)h8, rowptr, colidx, (uint2*)z, N_NODES);
    k_gemm<256, true, false><<<ggrid, 256, 0, stream>>>(z, W1t[1], bias1[1], y, nullptr);
    k_gemm<256, true, true ><<<ggrid, 256, 0, stream>>>(y, W2t[1], lw[1][7], h, h8);
    // layer 3: GEMM1 only; W2 folded with output head
    k_agg256<<<WBLOCKS, 256, 0, stream>>>((const uint2*)h, (const unsigned*)h8, rowptr, colidx, (uint2*)z, N_NODES);
    k_gemm<256, true, false><<<ggrid, 256, 0, stream>>>(z, W1t[2], bias1[2], y, nullptr);
    // head
    k_head<<<WBLOCKS, 256, 0, stream>>>((const uint2*)y, W2o, bo, (float*)d_out, N_NODES);
}

// Round 8
// 751.479 us; speedup vs baseline: 2.5310x; 1.0500x over previous
//
#include <hip/hip_runtime.h>
#include <cstdint>
#include <cstddef>

#define N_NODES 100000
#define N_EDGES 3200000
#define MPAD    100096   // 782 * 128
#define HID     256
#define NBUCK   196
#define BSH     9
#define BSTRIDE 18432

typedef _Float16 f16;
typedef _Float16 f16x2 __attribute__((ext_vector_type(2)));
typedef _Float16 f16x8 __attribute__((ext_vector_type(8)));
typedef float    f32x4 __attribute__((ext_vector_type(4)));

union F16x2 { unsigned u; f16 h[2]; f16x2 v; };
__device__ inline void unpack2(unsigned u, float& a, float& b) {
    F16x2 x; x.u = u; a = (float)x.h[0]; b = (float)x.h[1];
}
__device__ inline unsigned pack2(float a, float b) {
    F16x2 x; x.h[0] = (f16)a; x.h[1] = (f16)b; return x.u;
}
__device__ inline f16x2 asv(unsigned u) { F16x2 x; x.u = u; return x.v; }

// ---------------- CSR build: bucketed counting sort ----------------
__global__ __launch_bounds__(256) void k_bucketA(const int* __restrict__ src,
                                                 const int* __restrict__ dst,
                                                 unsigned* __restrict__ pairs,
                                                 int* __restrict__ nb, int e) {
    __shared__ int hist[NBUCK];
    __shared__ int lbase[NBUCK];
    __shared__ int lcur[NBUCK];
    const int t = threadIdx.x;
    for (int i = t; i < NBUCK; i += 256) hist[i] = 0;
    __syncthreads();
    const int e0 = blockIdx.x * 4096;
    bool v[16]; int d[16], s[16];
#pragma unroll
    for (int i = 0; i < 16; ++i) {
        int idx = e0 + i * 256 + t;
        v[i] = idx < e;
        d[i] = v[i] ? dst[idx] : 0;
        s[i] = v[i] ? src[idx] : 0;
    }
#pragma unroll
    for (int i = 0; i < 16; ++i)
        if (v[i]) atomicAdd(&hist[d[i] >> BSH], 1);
    __syncthreads();
    for (int i = t; i < NBUCK; i += 256) {
        int h = hist[i];
        lbase[i] = h ? atomicAdd(&nb[i], h) : 0;
        lcur[i] = 0;
    }
    __syncthreads();
#pragma unroll
    for (int i = 0; i < 16; ++i) {
        if (v[i]) {
            int b = d[i] >> BSH;
            int p = atomicAdd(&lcur[b], 1);
            unsigned packed = ((unsigned)(d[i] & 511) << 17) | (unsigned)s[i];
            pairs[(size_t)b * BSTRIDE + lbase[b] + p] = packed;
        }
    }
}

__global__ void k_scan196(const int* __restrict__ nb, int* __restrict__ bbase,
                          int* __restrict__ rowptrN) {
    __shared__ int s[256];
    int t = threadIdx.x;
    int v = (t < NBUCK) ? nb[t] : 0;
    s[t] = v;
    __syncthreads();
    for (int off = 1; off < 256; off <<= 1) {
        int u = (t >= off) ? s[t - off] : 0;
        __syncthreads();
        s[t] += u;
        __syncthreads();
    }
    if (t < NBUCK) bbase[t] = s[t] - v;
    if (t == 0) *rowptrN = N_EDGES;
}

__global__ __launch_bounds__(256) void k_bucketB(const unsigned* __restrict__ pairs,
                                                 const int* __restrict__ nb,
                                                 const int* __restrict__ bbase,
                                                 int* __restrict__ rowptr,
                                                 int* __restrict__ colidx) {
    __shared__ int deg[512];
    __shared__ int sc[512];
    __shared__ int cur[512];
    const int b = blockIdx.x, t = threadIdx.x;
    const int cnt = nb[b], base = bbase[b];
    const unsigned* P = pairs + (size_t)b * BSTRIDE;
    deg[t] = 0; deg[t + 256] = 0;
    __syncthreads();
    for (int i = t; i < cnt; i += 256) atomicAdd(&deg[P[i] >> 17], 1);
    __syncthreads();
    sc[t] = deg[t]; sc[t + 256] = deg[t + 256];
    __syncthreads();
    for (int off = 1; off < 512; off <<= 1) {
        int a0 = (t >= off) ? sc[t - off] : 0;
        int a1 = (t + 256 >= off) ? sc[t + 256 - off] : 0;
        __syncthreads();
        sc[t] += a0; sc[t + 256] += a1;
        __syncthreads();
    }
    int node0 = b << BSH;
#pragma unroll
    for (int rep = 0; rep < 2; ++rep) {
        int i = t + rep * 256;
        int excl = base + sc[i] - deg[i];
        cur[i] = excl;
        int node = node0 + i;
        if (node < N_NODES) rowptr[node] = excl;
    }
    __syncthreads();
    for (int i = t; i < cnt; i += 256) {
        unsigned p = P[i];
        int pos = atomicAdd(&cur[p >> 17], 1);
        colidx[pos] = (int)(p & 0x1FFFF);
    }
}

// ---------------- dtype prep ----------------
__global__ void k_cvt(const float2* __restrict__ x, unsigned* __restrict__ o, int n) {
    int t = blockIdx.x * 256 + threadIdx.x;
    if (t < n) { float2 v = x[t]; o[t] = pack2(v.x, v.y); }
}

__global__ void k_foldw1(const float* __restrict__ W, const float* __restrict__ b1,
                         const float* __restrict__ gm, const float* __restrict__ bt,
                         const float* __restrict__ mu, const float* __restrict__ vr,
                         f16* __restrict__ Wt, float* __restrict__ bias, int K) {
    int t = blockIdx.x * 256 + threadIdx.x;
    if (t >= K * 256) return;
    int n = t & 255, k = t >> 8;
    float sc = gm[n] * rsqrtf(vr[n] + 1e-5f);
    Wt[n * K + k] = (f16)(W[t] * sc);
    if (k == 0) bias[n] = (b1[n] - mu[n]) * sc + bt[n];
}

__global__ void k_transb(const float* __restrict__ W, f16* __restrict__ Wt) {
    int t = blockIdx.x * 256 + threadIdx.x;
    int n = t & 255, k = t >> 8;
    Wt[n * 256 + k] = (f16)W[t];
}

// W2o[k][o] = sum_j W2[k][j]*outW[j][o]; bo[o] = sum_j b2[j]*outW[j][o] + outb[o]
__global__ void k_fold2(const float* __restrict__ W2, const float* __restrict__ b2,
                        const float* __restrict__ outW, const float* __restrict__ outb,
                        float* __restrict__ W2o, float* __restrict__ bo) {
    int k = threadIdx.x;
    float a0 = 0.f, a1 = 0.f;
    for (int j = 0; j < 256; ++j) {
        float w = W2[k * 256 + j];
        a0 += w * outW[j * 2 + 0];
        a1 += w * outW[j * 2 + 1];
    }
    W2o[k * 2 + 0] = a0;
    W2o[k * 2 + 1] = a1;
    if (k < 2) {
        float b = outb[k];
        for (int j = 0; j < 256; ++j) b += b2[j] * outW[j * 2 + k];
        bo[k] = b;
    }
}

// ---------------- aggregation ----------------
// z = h + sum_{j->i} h_j, all reads from fp8 e4m3 table h8 (256 B/row).
// fp32 accumulate; z written f16 (GEMM A input).
__global__ void k_agg256(const unsigned* __restrict__ h8,
                         const int* __restrict__ rp, const int* __restrict__ ci,
                         uint2* __restrict__ z, int n) {
    int gw = (blockIdx.x * 256 + threadIdx.x) >> 6;
    if (gw >= n) return;
    int lane = threadIdx.x & 63;
    const unsigned* h8l = h8 + lane;   // lane's 4-byte slot of each 256 B row
    float a0, a1, a2, a3;
    {
        unsigned u = h8l[(size_t)gw * 64];   // self term (fp8: 1-of-33 terms, negligible)
        auto lo = __builtin_amdgcn_cvt_pk_f32_fp8(u, false);
        auto hi = __builtin_amdgcn_cvt_pk_f32_fp8(u, true);
        a0 = lo[0]; a1 = lo[1]; a2 = hi[0]; a3 = hi[1];
    }
    int s = rp[gw], e = rp[gw + 1];
    int p = s;
    for (; p + 7 < e; p += 8) {
        int j0 = ci[p],     j1 = ci[p + 1], j2 = ci[p + 2], j3 = ci[p + 3];
        int j4 = ci[p + 4], j5 = ci[p + 5], j6 = ci[p + 6], j7 = ci[p + 7];
        unsigned u0 = h8l[(size_t)j0 * 64], u1 = h8l[(size_t)j1 * 64];
        unsigned u2 = h8l[(size_t)j2 * 64], u3 = h8l[(size_t)j3 * 64];
        unsigned u4 = h8l[(size_t)j4 * 64], u5 = h8l[(size_t)j5 * 64];
        unsigned u6 = h8l[(size_t)j6 * 64], u7 = h8l[(size_t)j7 * 64];
#pragma unroll
        for (int q = 0; q < 8; ++q) {
            unsigned u = q == 0 ? u0 : q == 1 ? u1 : q == 2 ? u2 : q == 3 ? u3
                       : q == 4 ? u4 : q == 5 ? u5 : q == 6 ? u6 : u7;
            auto lo = __builtin_amdgcn_cvt_pk_f32_fp8(u, false);
            auto hi = __builtin_amdgcn_cvt_pk_f32_fp8(u, true);
            a0 += lo[0]; a1 += lo[1]; a2 += hi[0]; a3 += hi[1];
        }
    }
    for (; p < e; ++p) {
        unsigned u = h8l[(size_t)ci[p] * 64];
        auto lo = __builtin_amdgcn_cvt_pk_f32_fp8(u, false);
        auto hi = __builtin_amdgcn_cvt_pk_f32_fp8(u, true);
        a0 += lo[0]; a1 += lo[1]; a2 += hi[0]; a3 += hi[1];
    }
    uint2 o; o.x = pack2(a0, a1); o.y = pack2(a2, a3);
    z[(size_t)gw * 64 + lane] = o;
}

// layer-1: x stays fp16 (signed values -> cancellation amplifies fp8 error)
__global__ void k_agg128(const unsigned* __restrict__ h, const int* __restrict__ rp,
                         const int* __restrict__ ci, unsigned* __restrict__ z, int n) {
    int gw = (blockIdx.x * 256 + threadIdx.x) >> 6;
    if (gw >= n) return;
    int lane = threadIdx.x & 63;
    const unsigned* hl = h + lane;
    float a0, a1, t0, t1;
    unpack2(hl[(size_t)gw * 64], a0, a1);
    int s = rp[gw], e = rp[gw + 1];
    int p = s;
    for (; p + 7 < e; p += 8) {
        int j0 = ci[p],     j1 = ci[p + 1], j2 = ci[p + 2], j3 = ci[p + 3];
        int j4 = ci[p + 4], j5 = ci[p + 5], j6 = ci[p + 6], j7 = ci[p + 7];
        unsigned v0 = hl[(size_t)j0 * 64], v1 = hl[(size_t)j1 * 64];
        unsigned v2 = hl[(size_t)j2 * 64], v3 = hl[(size_t)j3 * 64];
        unsigned v4 = hl[(size_t)j4 * 64], v5 = hl[(size_t)j5 * 64];
        unsigned v6 = hl[(size_t)j6 * 64], v7 = hl[(size_t)j7 * 64];
        f16x2 sx = asv(v0);
        sx += asv(v1); sx += asv(v2); sx += asv(v3);
        sx += asv(v4); sx += asv(v5); sx += asv(v6); sx += asv(v7);
        a0 += (float)sx[0]; a1 += (float)sx[1];
    }
    for (; p < e; ++p) {
        unpack2(hl[(size_t)ci[p] * 64], t0, t1); a0 += t0; a1 += t1;
    }
    z[(size_t)gw * 64 + lane] = pack2(a0, a1);
}

// ---------------- GEMM: C[MPAD][256] = A[MPAD][K] @ Bt[256][K]^T (+bias, relu) ----------------
// 128M x 256N tile (full output width -> A read once). 4 waves of 64x128.
// ST16: write f16 C; ST8: write fp8 e4m3 C8 (gather table).
template <int K, bool RELU, bool ST16, bool ST8>
__global__ __launch_bounds__(256, 2) void k_gemm2(const f16* __restrict__ A,
                                                  const f16* __restrict__ Bt,
                                                  const float* __restrict__ bias,
                                                  f16* __restrict__ C,
                                                  unsigned char* __restrict__ C8) {
    __shared__ f16 As[128 * 64];   // 16 KB
    __shared__ f16 Bs[256 * 64];   // 32 KB
    const int tid = threadIdx.x;
    const int bm0 = blockIdx.x * 128;
    const int lane = tid & 63, wave = tid >> 6;
    const int quad = lane >> 4, l16 = lane & 15;
    const int wr = (wave >> 1) * 64;    // 64-row band
    const int wc = (wave & 1) * 128;    // 128-col band
    f32x4 acc[4][8] = {};
    const f16* Abase = A + (size_t)bm0 * K;

    for (int k0 = 0; k0 < K; k0 += 64) {
#pragma unroll
        for (int i = 0; i < 4; ++i) {   // A tile: 1024 chunks of 16 B
            int c = i * 256 + tid;
            int m = c >> 3;
            int gg = (c & 7) ^ (m & 7);
            __builtin_amdgcn_global_load_lds(
                (const __attribute__((address_space(1))) unsigned int*)(Abase + (size_t)m * K + k0 + gg * 8),
                (__attribute__((address_space(3))) unsigned int*)(As + (size_t)c * 8), 16, 0, 0);
        }
#pragma unroll
        for (int i = 0; i < 8; ++i) {   // B tile: 2048 chunks
            int c = i * 256 + tid;
            int m = c >> 3;
            int gg = (c & 7) ^ (m & 7);
            __builtin_amdgcn_global_load_lds(
                (const __attribute__((address_space(1))) unsigned int*)(Bt + (size_t)m * K + k0 + gg * 8),
                (__attribute__((address_space(3))) unsigned int*)(Bs + (size_t)c * 8), 16, 0, 0);
        }
        __syncthreads();
#pragma unroll
        for (int kk = 0; kk < 64; kk += 32) {
            const int gbase = kk >> 3;
            f16x8 af[4], bfv[8];
#pragma unroll
            for (int mi = 0; mi < 4; ++mi) {
                int m = wr + mi * 16 + l16;
                int slot = (gbase + quad) ^ (m & 7);
                af[mi] = *(const f16x8*)&As[(m * 8 + slot) * 8];
            }
#pragma unroll
            for (int ni = 0; ni < 8; ++ni) {
                int m = wc + ni * 16 + l16;
                int slot = (gbase + quad) ^ (m & 7);
                bfv[ni] = *(const f16x8*)&Bs[(m * 8 + slot) * 8];
            }
#pragma unroll
            for (int mi = 0; mi < 4; ++mi)
#pragma unroll
                for (int ni = 0; ni < 8; ++ni)
                    acc[mi][ni] = __builtin_amdgcn_mfma_f32_16x16x32_f16(af[mi], bfv[ni], acc[mi][ni], 0, 0, 0);
        }
        __syncthreads();
    }

    float bv[8];
#pragma unroll
    for (int ni = 0; ni < 8; ++ni) bv[ni] = bias[wc + ni * 16 + l16];
#pragma unroll
    for (int mi = 0; mi < 4; ++mi) {
#pragma unroll
        for (int r = 0; r < 4; ++r) {
            size_t row = (size_t)(bm0 + wr + mi * 16 + quad * 4 + r);
#pragma unroll
            for (int ni = 0; ni < 8; ++ni) {
                float v = acc[mi][ni][r] + bv[ni];
                if (RELU) v = fmaxf(v, 0.f);
                int col = wc + ni * 16 + l16;
                if (ST16) C[row * HID + col] = (f16)v;
                if (ST8) {
                    int pk = __builtin_amdgcn_cvt_pk_fp8_f32(v, v, 0, false);
                    C8[row * HID + col] = (unsigned char)(pk & 0xff);
                }
            }
        }
    }
}

// ---------------- head: out[N][2] = y[N][256] @ W2o[256][2] + bo ----------------
__global__ void k_head(const uint2* __restrict__ y, const float* __restrict__ W2o,
                       const float* __restrict__ bo, float* __restrict__ out, int n) {
    __shared__ float w[512];
    __shared__ float bb[2];
    int t = threadIdx.x;
    w[t] = W2o[t];
    w[t + 256] = W2o[t + 256];
    if (t < 2) bb[t] = bo[t];
    __syncthreads();
    int gw = (blockIdx.x * 256 + t) >> 6;
    if (gw >= n) return;
    int lane = t & 63;
    uint2 d = y[(size_t)gw * 64 + lane];
    float x0, x1, x2, x3;
    unpack2(d.x, x0, x1); unpack2(d.y, x2, x3);
    int k = lane * 4;
    float o0 = x0 * w[k * 2 + 0] + x1 * w[k * 2 + 2] + x2 * w[k * 2 + 4] + x3 * w[k * 2 + 6];
    float o1 = x0 * w[k * 2 + 1] + x1 * w[k * 2 + 3] + x2 * w[k * 2 + 5] + x3 * w[k * 2 + 7];
#pragma unroll
    for (int off = 32; off > 0; off >>= 1) {
        o0 += __shfl_down(o0, off);
        o1 += __shfl_down(o1, off);
    }
    if (lane == 0) {
        out[(size_t)gw * 2 + 0] = o0 + bb[0];
        out[(size_t)gw * 2 + 1] = o1 + bb[1];
    }
}

extern "C" void kernel_launch(void* const* d_in, const int* in_sizes, int n_in,
                              void* d_out, int out_size, void* d_ws, size_t ws_size,
                              hipStream_t stream) {
    const float* x    = (const float*)d_in[0];
    const int*   ei   = (const int*)d_in[1];
    const int*   esrc = ei;
    const int*   edst = ei + N_EDGES;
    const float* lw[3][8];
    for (int l = 0; l < 3; ++l)
        for (int j = 0; j < 8; ++j) lw[l][j] = (const float*)d_in[2 + l * 8 + j];
    const float* outW = (const float*)d_in[26];
    const float* outB = (const float*)d_in[27];

    char* base = (char*)d_ws;
    size_t off = 0;
    auto alloc = [&](size_t bytes) -> void* {
        void* r = base + off;
        off += (bytes + 255) & ~(size_t)255;
        return r;
    };
    f16* z  = (f16*)alloc((size_t)MPAD * 256 * 2);
    f16* y  = (f16*)alloc((size_t)MPAD * 256 * 2);
    unsigned char* h8 = (unsigned char*)alloc((size_t)MPAD * 256);
    f16* xh = (f16*)alloc((size_t)MPAD * 128 * 2);
    f16* W1t[3]; float* bias1[3]; f16* W2t[2];
    W1t[0] = (f16*)alloc(256 * 128 * 2);
    W1t[1] = (f16*)alloc(256 * 256 * 2);
    W1t[2] = (f16*)alloc(256 * 256 * 2);
    for (int l = 0; l < 2; ++l) W2t[l] = (f16*)alloc(256 * 256 * 2);
    for (int l = 0; l < 3; ++l) bias1[l] = (float*)alloc(256 * 4);
    float* W2o = (float*)alloc(512 * 4);
    float* bo  = (float*)alloc(2 * 4);
    unsigned* pairs = (unsigned*)alloc((size_t)NBUCK * BSTRIDE * 4);
    int* nb     = (int*)alloc(NBUCK * 4);
    int* bbase  = (int*)alloc(NBUCK * 4);
    int* rowptr = (int*)alloc((size_t)(N_NODES + 1) * 4);
    int* colidx = (int*)alloc((size_t)N_EDGES * 4);

    // CSR build
    hipMemsetAsync(nb, 0, NBUCK * 4, stream);
    k_bucketA<<<(N_EDGES + 4095) / 4096, 256, 0, stream>>>(esrc, edst, pairs, nb, N_EDGES);
    k_scan196<<<1, 256, 0, stream>>>(nb, bbase, rowptr + N_NODES);
    k_bucketB<<<NBUCK, 256, 0, stream>>>(pairs, nb, bbase, rowptr, colidx);

    // dtype prep + weight folds
    k_cvt<<<(N_NODES * 64 + 255) / 256, 256, 0, stream>>>((const float2*)x, (unsigned*)xh, N_NODES * 64);
    k_foldw1<<<128, 256, 0, stream>>>(lw[0][0], lw[0][1], lw[0][2], lw[0][3], lw[0][4], lw[0][5], W1t[0], bias1[0], 128);
    k_foldw1<<<256, 256, 0, stream>>>(lw[1][0], lw[1][1], lw[1][2], lw[1][3], lw[1][4], lw[1][5], W1t[1], bias1[1], 256);
    k_foldw1<<<256, 256, 0, stream>>>(lw[2][0], lw[2][1], lw[2][2], lw[2][3], lw[2][4], lw[2][5], W1t[2], bias1[2], 256);
    k_transb<<<256, 256, 0, stream>>>(lw[0][6], W2t[0]);
    k_transb<<<256, 256, 0, stream>>>(lw[1][6], W2t[1]);
    k_fold2<<<1, 256, 0, stream>>>(lw[2][6], lw[2][7], outW, outB, W2o, bo);

    const int GG = MPAD / 128;            // 782 blocks, full 256-wide output
    const int WBLOCKS = (N_NODES + 3) / 4;

    // layer 1
    k_agg128<<<WBLOCKS, 256, 0, stream>>>((const unsigned*)xh, rowptr, colidx, (unsigned*)z, N_NODES);
    k_gemm2<128, true, true,  false><<<GG, 256, 0, stream>>>(z, W1t[0], bias1[0], y, nullptr);
    k_gemm2<256, true, false, true ><<<GG, 256, 0, stream>>>(y, W2t[0], lw[0][7], nullptr, h8);
    // layer 2
    k_agg256<<<WBLOCKS, 256, 0, stream>>>((const unsigned*)h8, rowptr, colidx, (uint2*)z, N_NODES);
    k_gemm2<256, true, true,  false><<<GG, 256, 0, stream>>>(z, W1t[1], bias1[1], y, nullptr);
    k_gemm2<256, true, false, true ><<<GG, 256, 0, stream>>>(y, W2t[1], lw[1][7], nullptr, h8);
    // layer 3: GEMM1 only; W2 folded with output head
    k_agg256<<<WBLOCKS, 256, 0, stream>>>((const unsigned*)h8, rowptr, colidx, (uint2*)z, N_NODES);
    k_gemm2<256, true, true,  false><<<GG, 256, 0, stream>>>(z, W1t[2], bias1[2], y, nullptr);
    // head
    k_head<<<WBLOCKS, 256, 0, stream>>>((const uint2*)y, W2o, bo, (float*)d_out, N_NODES);
}

// Round 9
// 719.597 us; speedup vs baseline: 2.6431x; 1.0443x over previous
//
#include <hip/hip_runtime.h>
#include <cstdint>
#include <cstddef>

#define N_NODES 100000
#define N_EDGES 3200000
#define MPAD    100096   // 782 * 128
#define HID     256
#define NBUCK   196
#define BSH     9
#define BSTRIDE 18432

typedef _Float16 f16;
typedef _Float16 f16x2 __attribute__((ext_vector_type(2)));
typedef _Float16 f16x8 __attribute__((ext_vector_type(8)));
typedef float    f32x4 __attribute__((ext_vector_type(4)));
typedef float    f32x2 __attribute__((ext_vector_type(2)));

union F16x2 { unsigned u; f16 h[2]; f16x2 v; };
__device__ inline void unpack2(unsigned u, float& a, float& b) {
    F16x2 x; x.u = u; a = (float)x.h[0]; b = (float)x.h[1];
}
__device__ inline unsigned pack2(float a, float b) {
    F16x2 x; x.h[0] = (f16)a; x.h[1] = (f16)b; return x.u;
}

// ---------------- CSR build: bucketed counting sort ----------------
__global__ __launch_bounds__(256) void k_bucketA(const int* __restrict__ src,
                                                 const int* __restrict__ dst,
                                                 unsigned* __restrict__ pairs,
                                                 int* __restrict__ nb, int e) {
    __shared__ int hist[NBUCK];
    __shared__ int lbase[NBUCK];
    __shared__ int lcur[NBUCK];
    const int t = threadIdx.x;
    for (int i = t; i < NBUCK; i += 256) hist[i] = 0;
    __syncthreads();
    const int e0 = blockIdx.x * 4096;
    bool v[16]; int d[16], s[16];
#pragma unroll
    for (int i = 0; i < 16; ++i) {
        int idx = e0 + i * 256 + t;
        v[i] = idx < e;
        d[i] = v[i] ? dst[idx] : 0;
        s[i] = v[i] ? src[idx] : 0;
    }
#pragma unroll
    for (int i = 0; i < 16; ++i)
        if (v[i]) atomicAdd(&hist[d[i] >> BSH], 1);
    __syncthreads();
    for (int i = t; i < NBUCK; i += 256) {
        int h = hist[i];
        lbase[i] = h ? atomicAdd(&nb[i], h) : 0;
        lcur[i] = 0;
    }
    __syncthreads();
#pragma unroll
    for (int i = 0; i < 16; ++i) {
        if (v[i]) {
            int b = d[i] >> BSH;
            int p = atomicAdd(&lcur[b], 1);
            unsigned packed = ((unsigned)(d[i] & 511) << 17) | (unsigned)s[i];
            pairs[(size_t)b * BSTRIDE + lbase[b] + p] = packed;
        }
    }
}

__global__ void k_scan196(const int* __restrict__ nb, int* __restrict__ bbase,
                          int* __restrict__ rowptrN) {
    __shared__ int s[256];
    int t = threadIdx.x;
    int v = (t < NBUCK) ? nb[t] : 0;
    s[t] = v;
    __syncthreads();
    for (int off = 1; off < 256; off <<= 1) {
        int u = (t >= off) ? s[t - off] : 0;
        __syncthreads();
        s[t] += u;
        __syncthreads();
    }
    if (t < NBUCK) bbase[t] = s[t] - v;
    if (t == 0) *rowptrN = N_EDGES;
}

__global__ __launch_bounds__(256) void k_bucketB(const unsigned* __restrict__ pairs,
                                                 const int* __restrict__ nb,
                                                 const int* __restrict__ bbase,
                                                 int* __restrict__ rowptr,
                                                 int* __restrict__ colidx) {
    __shared__ int deg[512];
    __shared__ int sc[512];
    __shared__ int cur[512];
    const int b = blockIdx.x, t = threadIdx.x;
    const int cnt = nb[b], base = bbase[b];
    const unsigned* P = pairs + (size_t)b * BSTRIDE;
    deg[t] = 0; deg[t + 256] = 0;
    __syncthreads();
    for (int i = t; i < cnt; i += 256) atomicAdd(&deg[P[i] >> 17], 1);
    __syncthreads();
    sc[t] = deg[t]; sc[t + 256] = deg[t + 256];
    __syncthreads();
    for (int off = 1; off < 512; off <<= 1) {
        int a0 = (t >= off) ? sc[t - off] : 0;
        int a1 = (t + 256 >= off) ? sc[t + 256 - off] : 0;
        __syncthreads();
        sc[t] += a0; sc[t + 256] += a1;
        __syncthreads();
    }
    int node0 = b << BSH;
#pragma unroll
    for (int rep = 0; rep < 2; ++rep) {
        int i = t + rep * 256;
        int excl = base + sc[i] - deg[i];
        cur[i] = excl;
        int node = node0 + i;
        if (node < N_NODES) rowptr[node] = excl;
    }
    __syncthreads();
    // colidx stores src*64 (pre-scaled row offset: 64 lanes/row in both tables)
    for (int i = t; i < cnt; i += 256) {
        unsigned p = P[i];
        int pos = atomicAdd(&cur[p >> 17], 1);
        colidx[pos] = (int)(p & 0x1FFFF) << 6;
    }
}

// ---------------- dtype prep ----------------
// x fp32 [N][128] -> fp8 e4m3 table x8 [N][128] (128 B/row; lane = ushort)
__global__ void k_cvt8(const float2* __restrict__ x, unsigned short* __restrict__ o, int n) {
    int t = blockIdx.x * 256 + threadIdx.x;
    if (t < n) {
        float2 v = x[t];
        int pk = __builtin_amdgcn_cvt_pk_fp8_f32(v.x, v.y, 0, false);
        o[t] = (unsigned short)(pk & 0xffff);
    }
}

__global__ void k_foldw1(const float* __restrict__ W, const float* __restrict__ b1,
                         const float* __restrict__ gm, const float* __restrict__ bt,
                         const float* __restrict__ mu, const float* __restrict__ vr,
                         f16* __restrict__ Wt, float* __restrict__ bias, int K) {
    int t = blockIdx.x * 256 + threadIdx.x;
    if (t >= K * 256) return;
    int n = t & 255, k = t >> 8;
    float sc = gm[n] * rsqrtf(vr[n] + 1e-5f);
    Wt[n * K + k] = (f16)(W[t] * sc);
    if (k == 0) bias[n] = (b1[n] - mu[n]) * sc + bt[n];
}

__global__ void k_transb(const float* __restrict__ W, f16* __restrict__ Wt) {
    int t = blockIdx.x * 256 + threadIdx.x;
    int n = t & 255, k = t >> 8;
    Wt[n * 256 + k] = (f16)W[t];
}

// W2o[k][o] = sum_j W2[k][j]*outW[j][o]; bo[o] = sum_j b2[j]*outW[j][o] + outb[o]
__global__ void k_fold2(const float* __restrict__ W2, const float* __restrict__ b2,
                        const float* __restrict__ outW, const float* __restrict__ outb,
                        float* __restrict__ W2o, float* __restrict__ bo) {
    int k = threadIdx.x;
    float a0 = 0.f, a1 = 0.f;
    for (int j = 0; j < 256; ++j) {
        float w = W2[k * 256 + j];
        a0 += w * outW[j * 2 + 0];
        a1 += w * outW[j * 2 + 1];
    }
    W2o[k * 2 + 0] = a0;
    W2o[k * 2 + 1] = a1;
    if (k < 2) {
        float b = outb[k];
        for (int j = 0; j < 256; ++j) b += b2[j] * outW[j * 2 + k];
        bo[k] = b;
    }
}

// ---------------- aggregation ----------------
// z = h + sum_{j->i} h_j; reads fp8 e4m3 table h8 (256 B/row, lane = uint).
// float2 accumulators -> v_pk_add_f32. ci[] is pre-scaled src*64.
__global__ void k_agg256(const unsigned* __restrict__ h8,
                         const int* __restrict__ rp, const int* __restrict__ ci,
                         uint2* __restrict__ z, int n) {
    int gw = (blockIdx.x * 256 + threadIdx.x) >> 6;
    if (gw >= n) return;
    int lane = threadIdx.x & 63;
    const unsigned* h8l = h8 + lane;
    f32x2 A01, A23;
    {
        unsigned u = h8l[(size_t)gw * 64];   // self term
        A01 = __builtin_amdgcn_cvt_pk_f32_fp8(u, false);
        A23 = __builtin_amdgcn_cvt_pk_f32_fp8(u, true);
    }
    int s = rp[gw], e = rp[gw + 1];
    int p = s;
    for (; p + 7 < e; p += 8) {
        int j0 = ci[p],     j1 = ci[p + 1], j2 = ci[p + 2], j3 = ci[p + 3];
        int j4 = ci[p + 4], j5 = ci[p + 5], j6 = ci[p + 6], j7 = ci[p + 7];
        unsigned u0 = h8l[(size_t)j0], u1 = h8l[(size_t)j1];
        unsigned u2 = h8l[(size_t)j2], u3 = h8l[(size_t)j3];
        unsigned u4 = h8l[(size_t)j4], u5 = h8l[(size_t)j5];
        unsigned u6 = h8l[(size_t)j6], u7 = h8l[(size_t)j7];
#pragma unroll
        for (int q = 0; q < 8; ++q) {
            unsigned u = q == 0 ? u0 : q == 1 ? u1 : q == 2 ? u2 : q == 3 ? u3
                       : q == 4 ? u4 : q == 5 ? u5 : q == 6 ? u6 : u7;
            A01 += __builtin_amdgcn_cvt_pk_f32_fp8(u, false);
            A23 += __builtin_amdgcn_cvt_pk_f32_fp8(u, true);
        }
    }
    for (; p < e; ++p) {
        unsigned u = h8l[(size_t)ci[p]];
        A01 += __builtin_amdgcn_cvt_pk_f32_fp8(u, false);
        A23 += __builtin_amdgcn_cvt_pk_f32_fp8(u, true);
    }
    uint2 o; o.x = pack2(A01[0], A01[1]); o.y = pack2(A23[0], A23[1]);
    z[(size_t)gw * 64 + lane] = o;
}

// layer-1: fp8 x table (128 B/row, lane = ushort holding 2 fp8)
__global__ void k_agg128(const unsigned short* __restrict__ x8,
                         const int* __restrict__ rp, const int* __restrict__ ci,
                         unsigned* __restrict__ z, int n) {
    int gw = (blockIdx.x * 256 + threadIdx.x) >> 6;
    if (gw >= n) return;
    int lane = threadIdx.x & 63;
    const unsigned short* xl = x8 + lane;
    f32x2 A01 = __builtin_amdgcn_cvt_pk_f32_fp8((unsigned)xl[(size_t)gw * 64], false);
    int s = rp[gw], e = rp[gw + 1];
    int p = s;
    for (; p + 7 < e; p += 8) {
        int j0 = ci[p],     j1 = ci[p + 1], j2 = ci[p + 2], j3 = ci[p + 3];
        int j4 = ci[p + 4], j5 = ci[p + 5], j6 = ci[p + 6], j7 = ci[p + 7];
        unsigned u0 = xl[(size_t)j0], u1 = xl[(size_t)j1];
        unsigned u2 = xl[(size_t)j2], u3 = xl[(size_t)j3];
        unsigned u4 = xl[(size_t)j4], u5 = xl[(size_t)j5];
        unsigned u6 = xl[(size_t)j6], u7 = xl[(size_t)j7];
        A01 += __builtin_amdgcn_cvt_pk_f32_fp8(u0, false);
        A01 += __builtin_amdgcn_cvt_pk_f32_fp8(u1, false);
        A01 += __builtin_amdgcn_cvt_pk_f32_fp8(u2, false);
        A01 += __builtin_amdgcn_cvt_pk_f32_fp8(u3, false);
        A01 += __builtin_amdgcn_cvt_pk_f32_fp8(u4, false);
        A01 += __builtin_amdgcn_cvt_pk_f32_fp8(u5, false);
        A01 += __builtin_amdgcn_cvt_pk_f32_fp8(u6, false);
        A01 += __builtin_amdgcn_cvt_pk_f32_fp8(u7, false);
    }
    for (; p < e; ++p)
        A01 += __builtin_amdgcn_cvt_pk_f32_fp8((unsigned)xl[(size_t)ci[p]], false);
    z[(size_t)gw * 64 + lane] = pack2(A01[0], A01[1]);
}

// ---------------- GEMM: C[MPAD][256] = A[MPAD][K] @ Bt[256][K]^T (+bias, relu) ----------------
// 128M x 256N tile. ST16: write f16 C; ST8: write fp8 e4m3 C8 (gather table).
template <int K, bool RELU, bool ST16, bool ST8>
__global__ __launch_bounds__(256, 2) void k_gemm2(const f16* __restrict__ A,
                                                  const f16* __restrict__ Bt,
                                                  const float* __restrict__ bias,
                                                  f16* __restrict__ C,
                                                  unsigned char* __restrict__ C8) {
    __shared__ f16 As[128 * 64];   // 16 KB
    __shared__ f16 Bs[256 * 64];   // 32 KB
    const int tid = threadIdx.x;
    const int bm0 = blockIdx.x * 128;
    const int lane = tid & 63, wave = tid >> 6;
    const int quad = lane >> 4, l16 = lane & 15;
    const int wr = (wave >> 1) * 64;
    const int wc = (wave & 1) * 128;
    f32x4 acc[4][8] = {};
    const f16* Abase = A + (size_t)bm0 * K;

    for (int k0 = 0; k0 < K; k0 += 64) {
#pragma unroll
        for (int i = 0; i < 4; ++i) {
            int c = i * 256 + tid;
            int m = c >> 3;
            int gg = (c & 7) ^ (m & 7);
            __builtin_amdgcn_global_load_lds(
                (const __attribute__((address_space(1))) unsigned int*)(Abase + (size_t)m * K + k0 + gg * 8),
                (__attribute__((address_space(3))) unsigned int*)(As + (size_t)c * 8), 16, 0, 0);
        }
#pragma unroll
        for (int i = 0; i < 8; ++i) {
            int c = i * 256 + tid;
            int m = c >> 3;
            int gg = (c & 7) ^ (m & 7);
            __builtin_amdgcn_global_load_lds(
                (const __attribute__((address_space(1))) unsigned int*)(Bt + (size_t)m * K + k0 + gg * 8),
                (__attribute__((address_space(3))) unsigned int*)(Bs + (size_t)c * 8), 16, 0, 0);
        }
        __syncthreads();
#pragma unroll
        for (int kk = 0; kk < 64; kk += 32) {
            const int gbase = kk >> 3;
            f16x8 af[4], bfv[8];
#pragma unroll
            for (int mi = 0; mi < 4; ++mi) {
                int m = wr + mi * 16 + l16;
                int slot = (gbase + quad) ^ (m & 7);
                af[mi] = *(const f16x8*)&As[(m * 8 + slot) * 8];
            }
#pragma unroll
            for (int ni = 0; ni < 8; ++ni) {
                int m = wc + ni * 16 + l16;
                int slot = (gbase + quad) ^ (m & 7);
                bfv[ni] = *(const f16x8*)&Bs[(m * 8 + slot) * 8];
            }
#pragma unroll
            for (int mi = 0; mi < 4; ++mi)
#pragma unroll
                for (int ni = 0; ni < 8; ++ni)
                    acc[mi][ni] = __builtin_amdgcn_mfma_f32_16x16x32_f16(af[mi], bfv[ni], acc[mi][ni], 0, 0, 0);
        }
        __syncthreads();
    }

    float bv[8];
#pragma unroll
    for (int ni = 0; ni < 8; ++ni) bv[ni] = bias[wc + ni * 16 + l16];
#pragma unroll
    for (int mi = 0; mi < 4; ++mi) {
#pragma unroll
        for (int r = 0; r < 4; ++r) {
            size_t row = (size_t)(bm0 + wr + mi * 16 + quad * 4 + r);
#pragma unroll
            for (int ni = 0; ni < 8; ++ni) {
                float v = acc[mi][ni][r] + bv[ni];
                if (RELU) v = fmaxf(v, 0.f);
                int col = wc + ni * 16 + l16;
                if (ST16) C[row * HID + col] = (f16)v;
                if (ST8) {
                    int pk = __builtin_amdgcn_cvt_pk_fp8_f32(v, v, 0, false);
                    C8[row * HID + col] = (unsigned char)(pk & 0xff);
                }
            }
        }
    }
}

// ---------------- head: out[N][2] = y[N][256] @ W2o[256][2] + bo ----------------
__global__ void k_head(const uint2* __restrict__ y, const float* __restrict__ W2o,
                       const float* __restrict__ bo, float* __restrict__ out, int n) {
    __shared__ float w[512];
    __shared__ float bb[2];
    int t = threadIdx.x;
    w[t] = W2o[t];
    w[t + 256] = W2o[t + 256];
    if (t < 2) bb[t] = bo[t];
    __syncthreads();
    int gw = (blockIdx.x * 256 + t) >> 6;
    if (gw >= n) return;
    int lane = t & 63;
    uint2 d = y[(size_t)gw * 64 + lane];
    float x0, x1, x2, x3;
    unpack2(d.x, x0, x1); unpack2(d.y, x2, x3);
    int k = lane * 4;
    float o0 = x0 * w[k * 2 + 0] + x1 * w[k * 2 + 2] + x2 * w[k * 2 + 4] + x3 * w[k * 2 + 6];
    float o1 = x0 * w[k * 2 + 1] + x1 * w[k * 2 + 3] + x2 * w[k * 2 + 5] + x3 * w[k * 2 + 7];
#pragma unroll
    for (int off = 32; off > 0; off >>= 1) {
        o0 += __shfl_down(o0, off);
        o1 += __shfl_down(o1, off);
    }
    if (lane == 0) {
        out[(size_t)gw * 2 + 0] = o0 + bb[0];
        out[(size_t)gw * 2 + 1] = o1 + bb[1];
    }
}

extern "C" void kernel_launch(void* const* d_in, const int* in_sizes, int n_in,
                              void* d_out, int out_size, void* d_ws, size_t ws_size,
                              hipStream_t stream) {
    const float* x    = (const float*)d_in[0];
    const int*   ei   = (const int*)d_in[1];
    const int*   esrc = ei;
    const int*   edst = ei + N_EDGES;
    const float* lw[3][8];
    for (int l = 0; l < 3; ++l)
        for (int j = 0; j < 8; ++j) lw[l][j] = (const float*)d_in[2 + l * 8 + j];
    const float* outW = (const float*)d_in[26];
    const float* outB = (const float*)d_in[27];

    char* base = (char*)d_ws;
    size_t off = 0;
    auto alloc = [&](size_t bytes) -> void* {
        void* r = base + off;
        off += (bytes + 255) & ~(size_t)255;
        return r;
    };
    f16* z  = (f16*)alloc((size_t)MPAD * 256 * 2);
    f16* y  = (f16*)alloc((size_t)MPAD * 256 * 2);
    unsigned char* h8 = (unsigned char*)alloc((size_t)MPAD * 256);
    unsigned short* x8 = (unsigned short*)alloc((size_t)MPAD * 64 * 2);
    f16* W1t[3]; float* bias1[3]; f16* W2t[2];
    W1t[0] = (f16*)alloc(256 * 128 * 2);
    W1t[1] = (f16*)alloc(256 * 256 * 2);
    W1t[2] = (f16*)alloc(256 * 256 * 2);
    for (int l = 0; l < 2; ++l) W2t[l] = (f16*)alloc(256 * 256 * 2);
    for (int l = 0; l < 3; ++l) bias1[l] = (float*)alloc(256 * 4);
    float* W2o = (float*)alloc(512 * 4);
    float* bo  = (float*)alloc(2 * 4);
    unsigned* pairs = (unsigned*)alloc((size_t)NBUCK * BSTRIDE * 4);
    int* nb     = (int*)alloc(NBUCK * 4);
    int* bbase  = (int*)alloc(NBUCK * 4);
    int* rowptr = (int*)alloc((size_t)(N_NODES + 1) * 4);
    int* colidx = (int*)alloc((size_t)N_EDGES * 4);

    // CSR build
    hipMemsetAsync(nb, 0, NBUCK * 4, stream);
    k_bucketA<<<(N_EDGES + 4095) / 4096, 256, 0, stream>>>(esrc, edst, pairs, nb, N_EDGES);
    k_scan196<<<1, 256, 0, stream>>>(nb, bbase, rowptr + N_NODES);
    k_bucketB<<<NBUCK, 256, 0, stream>>>(pairs, nb, bbase, rowptr, colidx);

    // dtype prep + weight folds
    k_cvt8<<<(N_NODES * 64 + 255) / 256, 256, 0, stream>>>((const float2*)x, x8, N_NODES * 64);
    k_foldw1<<<128, 256, 0, stream>>>(lw[0][0], lw[0][1], lw[0][2], lw[0][3], lw[0][4], lw[0][5], W1t[0], bias1[0], 128);
    k_foldw1<<<256, 256, 0, stream>>>(lw[1][0], lw[1][1], lw[1][2], lw[1][3], lw[1][4], lw[1][5], W1t[1], bias1[1], 256);
    k_foldw1<<<256, 256, 0, stream>>>(lw[2][0], lw[2][1], lw[2][2], lw[2][3], lw[2][4], lw[2][5], W1t[2], bias1[2], 256);
    k_transb<<<256, 256, 0, stream>>>(lw[0][6], W2t[0]);
    k_transb<<<256, 256, 0, stream>>>(lw[1][6], W2t[1]);
    k_fold2<<<1, 256, 0, stream>>>(lw[2][6], lw[2][7], outW, outB, W2o, bo);

    const int GG = MPAD / 128;
    const int WBLOCKS = (N_NODES + 3) / 4;

    // layer 1
    k_agg128<<<WBLOCKS, 256, 0, stream>>>(x8, rowptr, colidx, (unsigned*)z, N_NODES);
    k_gemm2<128, true, true,  false><<<GG, 256, 0, stream>>>(z, W1t[0], bias1[0], y, nullptr);
    k_gemm2<256, true, false, true ><<<GG, 256, 0, stream>>>(y, W2t[0], lw[0][7], nullptr, h8);
    // layer 2
    k_agg256<<<WBLOCKS, 256, 0, stream>>>((const unsigned*)h8, rowptr, colidx, (uint2*)z, N_NODES);
    k_gemm2<256, true, true,  false><<<GG, 256, 0, stream>>>(z, W1t[1], bias1[1], y, nullptr);
    k_gemm2<256, true, false, true ><<<GG, 256, 0, stream>>>(y, W2t[1], lw[1][7], nullptr, h8);
    // layer 3: GEMM1 only; W2 folded with output head
    k_agg256<<<WBLOCKS, 256, 0, stream>>>((const unsigned*)h8, rowptr, colidx, (uint2*)z, N_NODES);
    k_gemm2<256, true, true,  false><<<GG, 256, 0, stream>>>(z, W1t[2], bias1[2], y, nullptr);
    // head
    k_head<<<WBLOCKS, 256, 0, stream>>>((const uint2*)y, W2o, bo, (float*)d_out, N_NODES);
}

// Round 10
// 686.379 us; speedup vs baseline: 2.7711x; 1.0484x over previous
//
#include <hip/hip_runtime.h>
#include <cstdint>
#include <cstddef>

#define N_NODES 100000
#define N_EDGES 3200000
#define MPAD    100096   // 782 * 128
#define HID     256
#define NBUCK   196
#define BSH     9
#define BSTRIDE 18432

typedef _Float16 f16;
typedef _Float16 f16x2 __attribute__((ext_vector_type(2)));
typedef _Float16 f16x8 __attribute__((ext_vector_type(8)));
typedef float    f32x4 __attribute__((ext_vector_type(4)));
typedef float    f32x2 __attribute__((ext_vector_type(2)));
typedef long long i64;

union F16x2 { unsigned u; f16 h[2]; f16x2 v; };
__device__ inline unsigned pack2(float a, float b) {
    F16x2 x; x.h[0] = (f16)a; x.h[1] = (f16)b; return x.u;
}
__device__ inline void unpack2(unsigned u, float& a, float& b) {
    F16x2 x; x.u = u; a = (float)x.h[0]; b = (float)x.h[1];
}

// ---------------- CSR build: bucketed counting sort ----------------
__global__ __launch_bounds__(256) void k_bucketA(const int* __restrict__ src,
                                                 const int* __restrict__ dst,
                                                 unsigned* __restrict__ pairs,
                                                 int* __restrict__ nb, int e) {
    __shared__ int hist[NBUCK];
    __shared__ int lbase[NBUCK];
    __shared__ int lcur[NBUCK];
    const int t = threadIdx.x;
    for (int i = t; i < NBUCK; i += 256) hist[i] = 0;
    __syncthreads();
    const int e0 = blockIdx.x * 4096;
    bool v[16]; int d[16], s[16];
#pragma unroll
    for (int i = 0; i < 16; ++i) {
        int idx = e0 + i * 256 + t;
        v[i] = idx < e;
        d[i] = v[i] ? dst[idx] : 0;
        s[i] = v[i] ? src[idx] : 0;
    }
#pragma unroll
    for (int i = 0; i < 16; ++i)
        if (v[i]) atomicAdd(&hist[d[i] >> BSH], 1);
    __syncthreads();
    for (int i = t; i < NBUCK; i += 256) {
        int h = hist[i];
        lbase[i] = h ? atomicAdd(&nb[i], h) : 0;
        lcur[i] = 0;
    }
    __syncthreads();
#pragma unroll
    for (int i = 0; i < 16; ++i) {
        if (v[i]) {
            int b = d[i] >> BSH;
            int p = atomicAdd(&lcur[b], 1);
            unsigned packed = ((unsigned)(d[i] & 511) << 17) | (unsigned)s[i];
            pairs[(size_t)b * BSTRIDE + lbase[b] + p] = packed;
        }
    }
}

__global__ void k_scan196(const int* __restrict__ nb, int* __restrict__ bbase,
                          int* __restrict__ rowptrN) {
    __shared__ int s[256];
    int t = threadIdx.x;
    int v = (t < NBUCK) ? nb[t] : 0;
    s[t] = v;
    __syncthreads();
    for (int off = 1; off < 256; off <<= 1) {
        int u = (t >= off) ? s[t - off] : 0;
        __syncthreads();
        s[t] += u;
        __syncthreads();
    }
    if (t < NBUCK) bbase[t] = s[t] - v;
    if (t == 0) *rowptrN = N_EDGES;
}

__global__ __launch_bounds__(256) void k_bucketB(const unsigned* __restrict__ pairs,
                                                 const int* __restrict__ nb,
                                                 const int* __restrict__ bbase,
                                                 int* __restrict__ rowptr,
                                                 int* __restrict__ colidx) {
    __shared__ int deg[512];
    __shared__ int sc[512];
    __shared__ int cur[512];
    const int b = blockIdx.x, t = threadIdx.x;
    const int cnt = nb[b], base = bbase[b];
    const unsigned* P = pairs + (size_t)b * BSTRIDE;
    deg[t] = 0; deg[t + 256] = 0;
    __syncthreads();
    for (int i = t; i < cnt; i += 256) atomicAdd(&deg[P[i] >> 17], 1);
    __syncthreads();
    sc[t] = deg[t]; sc[t + 256] = deg[t + 256];
    __syncthreads();
    for (int off = 1; off < 512; off <<= 1) {
        int a0 = (t >= off) ? sc[t - off] : 0;
        int a1 = (t + 256 >= off) ? sc[t + 256 - off] : 0;
        __syncthreads();
        sc[t] += a0; sc[t + 256] += a1;
        __syncthreads();
    }
    int node0 = b << BSH;
#pragma unroll
    for (int rep = 0; rep < 2; ++rep) {
        int i = t + rep * 256;
        int excl = base + sc[i] - deg[i];
        cur[i] = excl;
        int node = node0 + i;
        if (node < N_NODES) rowptr[node] = excl;
    }
    __syncthreads();
    // colidx stores src*64 (pre-scaled row offset: 64 lanes/row in both tables)
    for (int i = t; i < cnt; i += 256) {
        unsigned p = P[i];
        int pos = atomicAdd(&cur[p >> 17], 1);
        colidx[pos] = (int)(p & 0x1FFFF) << 6;
    }
}

// ---------------- dtype prep ----------------
__global__ void k_cvt8(const float2* __restrict__ x, unsigned short* __restrict__ o, int n) {
    int t = blockIdx.x * 256 + threadIdx.x;
    if (t < n) {
        float2 v = x[t];
        int pk = __builtin_amdgcn_cvt_pk_fp8_f32(v.x, v.y, 0, false);
        o[t] = (unsigned short)(pk & 0xffff);
    }
}

__global__ void k_foldw1(const float* __restrict__ W, const float* __restrict__ b1,
                         const float* __restrict__ gm, const float* __restrict__ bt,
                         const float* __restrict__ mu, const float* __restrict__ vr,
                         f16* __restrict__ Wt, float* __restrict__ bias, int K) {
    int t = blockIdx.x * 256 + threadIdx.x;
    if (t >= K * 256) return;
    int n = t & 255, k = t >> 8;
    float sc = gm[n] * rsqrtf(vr[n] + 1e-5f);
    Wt[n * K + k] = (f16)(W[t] * sc);
    if (k == 0) bias[n] = (b1[n] - mu[n]) * sc + bt[n];
}

// W2 f32 [k][n] -> fp8 e4m3 transposed [n][256]
__global__ void k_transb8(const float* __restrict__ W, unsigned char* __restrict__ W8) {
    int t = blockIdx.x * 256 + threadIdx.x;   // 65536
    int n = t & 255, k = t >> 8;
    float v = W[t];
    int pk = __builtin_amdgcn_cvt_pk_fp8_f32(v, v, 0, false);
    W8[n * 256 + k] = (unsigned char)(pk & 0xff);
}

// W2o[k][o] = sum_j W2[k][j]*outW[j][o]; bo[o] = sum_j b2[j]*outW[j][o] + outb[o]
__global__ void k_fold2(const float* __restrict__ W2, const float* __restrict__ b2,
                        const float* __restrict__ outW, const float* __restrict__ outb,
                        float* __restrict__ W2o, float* __restrict__ bo) {
    int k = threadIdx.x;
    float a0 = 0.f, a1 = 0.f;
    for (int j = 0; j < 256; ++j) {
        float w = W2[k * 256 + j];
        a0 += w * outW[j * 2 + 0];
        a1 += w * outW[j * 2 + 1];
    }
    W2o[k * 2 + 0] = a0;
    W2o[k * 2 + 1] = a1;
    if (k < 2) {
        float b = outb[k];
        for (int j = 0; j < 256; ++j) b += b2[j] * outW[j * 2 + k];
        bo[k] = b;
    }
}

// ---------------- aggregation (unchanged from R9) ----------------
__global__ void k_agg256(const unsigned* __restrict__ h8,
                         const int* __restrict__ rp, const int* __restrict__ ci,
                         uint2* __restrict__ z, int n) {
    int gw = (blockIdx.x * 256 + threadIdx.x) >> 6;
    if (gw >= n) return;
    int lane = threadIdx.x & 63;
    const unsigned* h8l = h8 + lane;
    f32x2 A01, A23;
    {
        unsigned u = h8l[(size_t)gw * 64];
        A01 = __builtin_amdgcn_cvt_pk_f32_fp8(u, false);
        A23 = __builtin_amdgcn_cvt_pk_f32_fp8(u, true);
    }
    int s = rp[gw], e = rp[gw + 1];
    int p = s;
    for (; p + 7 < e; p += 8) {
        int j0 = ci[p],     j1 = ci[p + 1], j2 = ci[p + 2], j3 = ci[p + 3];
        int j4 = ci[p + 4], j5 = ci[p + 5], j6 = ci[p + 6], j7 = ci[p + 7];
        unsigned u0 = h8l[(size_t)j0], u1 = h8l[(size_t)j1];
        unsigned u2 = h8l[(size_t)j2], u3 = h8l[(size_t)j3];
        unsigned u4 = h8l[(size_t)j4], u5 = h8l[(size_t)j5];
        unsigned u6 = h8l[(size_t)j6], u7 = h8l[(size_t)j7];
#pragma unroll
        for (int q = 0; q < 8; ++q) {
            unsigned u = q == 0 ? u0 : q == 1 ? u1 : q == 2 ? u2 : q == 3 ? u3
                       : q == 4 ? u4 : q == 5 ? u5 : q == 6 ? u6 : u7;
            A01 += __builtin_amdgcn_cvt_pk_f32_fp8(u, false);
            A23 += __builtin_amdgcn_cvt_pk_f32_fp8(u, true);
        }
    }
    for (; p < e; ++p) {
        unsigned u = h8l[(size_t)ci[p]];
        A01 += __builtin_amdgcn_cvt_pk_f32_fp8(u, false);
        A23 += __builtin_amdgcn_cvt_pk_f32_fp8(u, true);
    }
    uint2 o; o.x = pack2(A01[0], A01[1]); o.y = pack2(A23[0], A23[1]);
    z[(size_t)gw * 64 + lane] = o;
}

__global__ void k_agg128(const unsigned short* __restrict__ x8,
                         const int* __restrict__ rp, const int* __restrict__ ci,
                         unsigned* __restrict__ z, int n) {
    int gw = (blockIdx.x * 256 + threadIdx.x) >> 6;
    if (gw >= n) return;
    int lane = threadIdx.x & 63;
    const unsigned short* xl = x8 + lane;
    f32x2 A01 = __builtin_amdgcn_cvt_pk_f32_fp8((unsigned)xl[(size_t)gw * 64], false);
    int s = rp[gw], e = rp[gw + 1];
    int p = s;
    for (; p + 7 < e; p += 8) {
        int j0 = ci[p],     j1 = ci[p + 1], j2 = ci[p + 2], j3 = ci[p + 3];
        int j4 = ci[p + 4], j5 = ci[p + 5], j6 = ci[p + 6], j7 = ci[p + 7];
        unsigned u0 = xl[(size_t)j0], u1 = xl[(size_t)j1];
        unsigned u2 = xl[(size_t)j2], u3 = xl[(size_t)j3];
        unsigned u4 = xl[(size_t)j4], u5 = xl[(size_t)j5];
        unsigned u6 = xl[(size_t)j6], u7 = xl[(size_t)j7];
        A01 += __builtin_amdgcn_cvt_pk_f32_fp8(u0, false);
        A01 += __builtin_amdgcn_cvt_pk_f32_fp8(u1, false);
        A01 += __builtin_amdgcn_cvt_pk_f32_fp8(u2, false);
        A01 += __builtin_amdgcn_cvt_pk_f32_fp8(u3, false);
        A01 += __builtin_amdgcn_cvt_pk_f32_fp8(u4, false);
        A01 += __builtin_amdgcn_cvt_pk_f32_fp8(u5, false);
        A01 += __builtin_amdgcn_cvt_pk_f32_fp8(u6, false);
        A01 += __builtin_amdgcn_cvt_pk_f32_fp8(u7, false);
    }
    for (; p < e; ++p)
        A01 += __builtin_amdgcn_cvt_pk_f32_fp8((unsigned)xl[(size_t)ci[p]], false);
    z[(size_t)gw * 64 + lane] = pack2(A01[0], A01[1]);
}

// ---------------- fused layer: h8 = relu(relu(z@W1+b1)@W2+b2) ----------------
// Phase 1: f16 MFMA, A=z staged via global_load_lds, B=W1t f16.
// y -> fp8 into LDS Ys (swizzled: byte = row*256 + (g^(row&15))*8 + j).
// Phase 2: fp8 MFMA, A=Ys (ds_read_b64), B=W28 fp8 staged into dead As region.
template <int K>
__global__ __launch_bounds__(256, 2) void k_layer(const f16* __restrict__ A,
                                                  const f16* __restrict__ W1,
                                                  const float* __restrict__ b1,
                                                  const unsigned char* __restrict__ W28,
                                                  const float* __restrict__ b2,
                                                  unsigned char* __restrict__ H8) {
    __shared__ f16 As[128 * 64];            // 16 KB (phase2: W28 chunk region)
    __shared__ f16 Bs[256 * 64];            // 32 KB
    __shared__ unsigned char Ys[128 * 256]; // 32 KB (y fp8)
    const int tid = threadIdx.x;
    const int bm0 = blockIdx.x * 128;
    const int lane = tid & 63, wave = tid >> 6;
    const int quad = lane >> 4, l16 = lane & 15;
    const int wr = (wave >> 1) * 64;
    const int wc = (wave & 1) * 128;
    const f16* Abase = A + (size_t)bm0 * K;

    // ---- phase 1: f16 GEMM ----
    {
        f32x4 acc[4][8] = {};
        for (int k0 = 0; k0 < K; k0 += 64) {
#pragma unroll
            for (int i = 0; i < 4; ++i) {
                int c = i * 256 + tid;
                int m = c >> 3;
                int gg = (c & 7) ^ (m & 7);
                __builtin_amdgcn_global_load_lds(
                    (const __attribute__((address_space(1))) unsigned int*)(Abase + (size_t)m * K + k0 + gg * 8),
                    (__attribute__((address_space(3))) unsigned int*)(As + (size_t)c * 8), 16, 0, 0);
            }
#pragma unroll
            for (int i = 0; i < 8; ++i) {
                int c = i * 256 + tid;
                int m = c >> 3;
                int gg = (c & 7) ^ (m & 7);
                __builtin_amdgcn_global_load_lds(
                    (const __attribute__((address_space(1))) unsigned int*)(W1 + (size_t)m * K + k0 + gg * 8),
                    (__attribute__((address_space(3))) unsigned int*)(Bs + (size_t)c * 8), 16, 0, 0);
            }
            __syncthreads();
#pragma unroll
            for (int kk = 0; kk < 64; kk += 32) {
                const int gbase = kk >> 3;
                f16x8 af[4], bfv[8];
#pragma unroll
                for (int mi = 0; mi < 4; ++mi) {
                    int m = wr + mi * 16 + l16;
                    int slot = (gbase + quad) ^ (m & 7);
                    af[mi] = *(const f16x8*)&As[(m * 8 + slot) * 8];
                }
#pragma unroll
                for (int ni = 0; ni < 8; ++ni) {
                    int m = wc + ni * 16 + l16;
                    int slot = (gbase + quad) ^ (m & 7);
                    bfv[ni] = *(const f16x8*)&Bs[(m * 8 + slot) * 8];
                }
#pragma unroll
                for (int mi = 0; mi < 4; ++mi)
#pragma unroll
                    for (int ni = 0; ni < 8; ++ni)
                        acc[mi][ni] = __builtin_amdgcn_mfma_f32_16x16x32_f16(af[mi], bfv[ni], acc[mi][ni], 0, 0, 0);
            }
            __syncthreads();
        }
        // epilogue: y = relu(acc + b1) -> fp8 into Ys (swizzled)
        float bv[8];
#pragma unroll
        for (int ni = 0; ni < 8; ++ni) bv[ni] = b1[wc + ni * 16 + l16];
#pragma unroll
        for (int mi = 0; mi < 4; ++mi) {
#pragma unroll
            for (int r = 0; r < 4; ++r) {
                int row = wr + mi * 16 + quad * 4 + r;   // block-relative
#pragma unroll
                for (int ni = 0; ni < 8; ++ni) {
                    float v = fmaxf(acc[mi][ni][r] + bv[ni], 0.f);
                    int col = wc + ni * 16 + l16;
                    int pk = __builtin_amdgcn_cvt_pk_fp8_f32(v, v, 0, false);
                    int g = col >> 3, j = col & 7;
                    Ys[row * 256 + ((g ^ (row & 15)) * 8 + j)] = (unsigned char)(pk & 0xff);
                }
            }
        }
    }
    __syncthreads();

    // ---- phase 2: fp8 GEMM (K2 = 256) ----
    unsigned char* B8 = (unsigned char*)As;
    f32x4 acc2[4][8] = {};
    for (int k0 = 0; k0 < 256; k0 += 64) {
#pragma unroll
        for (int i = 0; i < 4; ++i) {       // 1024 chunks of 16 B: W28[n][64 per chunk]
            int c = i * 256 + tid;
            int n = c >> 2;
            int cg = c & 3;
            int gg = cg ^ (n & 3);
            __builtin_amdgcn_global_load_lds(
                (const __attribute__((address_space(1))) unsigned int*)(W28 + (size_t)n * 256 + k0 + gg * 16),
                (__attribute__((address_space(3))) unsigned int*)(B8 + (size_t)c * 16), 16, 0, 0);
        }
        __syncthreads();
#pragma unroll
        for (int kk = 0; kk < 64; kk += 32) {
            int gq = (kk >> 3) + quad;              // local k-group 0..7
            int gglob = ((k0 + kk) >> 3) + quad;    // global k-group 0..31
            i64 af[4], bf[8];
#pragma unroll
            for (int mi = 0; mi < 4; ++mi) {
                int m = wr + mi * 16 + l16;
                af[mi] = *(const i64*)&Ys[m * 256 + ((gglob ^ (m & 15)) * 8)];
            }
#pragma unroll
            for (int ni = 0; ni < 8; ++ni) {
                int n = wc + ni * 16 + l16;
                int cg2 = gq >> 1, sub = gq & 1;
                bf[ni] = *(const i64*)&B8[n * 64 + (cg2 ^ (n & 3)) * 16 + sub * 8];
            }
#pragma unroll
            for (int mi = 0; mi < 4; ++mi)
#pragma unroll
                for (int ni = 0; ni < 8; ++ni)
                    acc2[mi][ni] = __builtin_amdgcn_mfma_f32_16x16x32_fp8_fp8(af[mi], bf[ni], acc2[mi][ni], 0, 0, 0);
        }
        __syncthreads();
    }
    // epilogue: h8 = fp8(relu(acc2 + b2))
    float bv2[8];
#pragma unroll
    for (int ni = 0; ni < 8; ++ni) bv2[ni] = b2[wc + ni * 16 + l16];
#pragma unroll
    for (int mi = 0; mi < 4; ++mi) {
#pragma unroll
        for (int r = 0; r < 4; ++r) {
            size_t row = (size_t)(bm0 + wr + mi * 16 + quad * 4 + r);
#pragma unroll
            for (int ni = 0; ni < 8; ++ni) {
                float v = fmaxf(acc2[mi][ni][r] + bv2[ni], 0.f);
                int col = wc + ni * 16 + l16;
                int pk = __builtin_amdgcn_cvt_pk_fp8_f32(v, v, 0, false);
                H8[row * HID + col] = (unsigned char)(pk & 0xff);
            }
        }
    }
}

// ---------------- fused layer 3: out = relu(z@W1+b1) @ W2o + bo ----------------
__global__ __launch_bounds__(256, 2) void k_layer3(const f16* __restrict__ A,
                                                   const f16* __restrict__ W1,
                                                   const float* __restrict__ b1,
                                                   const float* __restrict__ W2o,
                                                   const float* __restrict__ bo,
                                                   float* __restrict__ out) {
    __shared__ f16 As[128 * 64];
    __shared__ f16 Bs[256 * 64];
    __shared__ float W2s[512];
    __shared__ float ob[256];    // [128 rows][2]
    const int tid = threadIdx.x;
    const int bm0 = blockIdx.x * 128;
    const int lane = tid & 63, wave = tid >> 6;
    const int quad = lane >> 4, l16 = lane & 15;
    const int wr = (wave >> 1) * 64;
    const int wc = (wave & 1) * 128;
    const f16* Abase = A + (size_t)bm0 * 256;
    W2s[tid] = W2o[tid];
    W2s[tid + 256] = W2o[tid + 256];
    ob[tid] = 0.f;

    f32x4 acc[4][8] = {};
    for (int k0 = 0; k0 < 256; k0 += 64) {
#pragma unroll
        for (int i = 0; i < 4; ++i) {
            int c = i * 256 + tid;
            int m = c >> 3;
            int gg = (c & 7) ^ (m & 7);
            __builtin_amdgcn_global_load_lds(
                (const __attribute__((address_space(1))) unsigned int*)(Abase + (size_t)m * 256 + k0 + gg * 8),
                (__attribute__((address_space(3))) unsigned int*)(As + (size_t)c * 8), 16, 0, 0);
        }
#pragma unroll
        for (int i = 0; i < 8; ++i) {
            int c = i * 256 + tid;
            int m = c >> 3;
            int gg = (c & 7) ^ (m & 7);
            __builtin_amdgcn_global_load_lds(
                (const __attribute__((address_space(1))) unsigned int*)(W1 + (size_t)m * 256 + k0 + gg * 8),
                (__attribute__((address_space(3))) unsigned int*)(Bs + (size_t)c * 8), 16, 0, 0);
        }
        __syncthreads();
#pragma unroll
        for (int kk = 0; kk < 64; kk += 32) {
            const int gbase = kk >> 3;
            f16x8 af[4], bfv[8];
#pragma unroll
            for (int mi = 0; mi < 4; ++mi) {
                int m = wr + mi * 16 + l16;
                int slot = (gbase + quad) ^ (m & 7);
                af[mi] = *(const f16x8*)&As[(m * 8 + slot) * 8];
            }
#pragma unroll
            for (int ni = 0; ni < 8; ++ni) {
                int m = wc + ni * 16 + l16;
                int slot = (gbase + quad) ^ (m & 7);
                bfv[ni] = *(const f16x8*)&Bs[(m * 8 + slot) * 8];
            }
#pragma unroll
            for (int mi = 0; mi < 4; ++mi)
#pragma unroll
                for (int ni = 0; ni < 8; ++ni)
                    acc[mi][ni] = __builtin_amdgcn_mfma_f32_16x16x32_f16(af[mi], bfv[ni], acc[mi][ni], 0, 0, 0);
        }
        __syncthreads();
    }
    // head: per-row partial dot with W2o, reduce across l16, accumulate in LDS
    float bv[8];
#pragma unroll
    for (int ni = 0; ni < 8; ++ni) bv[ni] = b1[wc + ni * 16 + l16];
#pragma unroll
    for (int mi = 0; mi < 4; ++mi) {
#pragma unroll
        for (int r = 0; r < 4; ++r) {
            int row = wr + mi * 16 + quad * 4 + r;   // block-relative
            float p0 = 0.f, p1 = 0.f;
#pragma unroll
            for (int ni = 0; ni < 8; ++ni) {
                float v = fmaxf(acc[mi][ni][r] + bv[ni], 0.f);
                int col = wc + ni * 16 + l16;
                p0 += v * W2s[col * 2 + 0];
                p1 += v * W2s[col * 2 + 1];
            }
#pragma unroll
            for (int off = 1; off <= 8; off <<= 1) {
                p0 += __shfl_xor(p0, off);
                p1 += __shfl_xor(p1, off);
            }
            if (l16 == 0) {
                atomicAdd(&ob[row * 2 + 0], p0);
                atomicAdd(&ob[row * 2 + 1], p1);
            }
        }
    }
    __syncthreads();
    int row = tid >> 1, o = tid & 1;
    if (bm0 + row < N_NODES)
        out[(size_t)(bm0 + row) * 2 + o] = ob[tid] + bo[o];
}

extern "C" void kernel_launch(void* const* d_in, const int* in_sizes, int n_in,
                              void* d_out, int out_size, void* d_ws, size_t ws_size,
                              hipStream_t stream) {
    const float* x    = (const float*)d_in[0];
    const int*   ei   = (const int*)d_in[1];
    const int*   esrc = ei;
    const int*   edst = ei + N_EDGES;
    const float* lw[3][8];
    for (int l = 0; l < 3; ++l)
        for (int j = 0; j < 8; ++j) lw[l][j] = (const float*)d_in[2 + l * 8 + j];
    const float* outW = (const float*)d_in[26];
    const float* outB = (const float*)d_in[27];

    char* base = (char*)d_ws;
    size_t off = 0;
    auto alloc = [&](size_t bytes) -> void* {
        void* r = base + off;
        off += (bytes + 255) & ~(size_t)255;
        return r;
    };
    f16* z  = (f16*)alloc((size_t)MPAD * 256 * 2);
    unsigned char* h8 = (unsigned char*)alloc((size_t)MPAD * 256);
    unsigned short* x8 = (unsigned short*)alloc((size_t)MPAD * 64 * 2);
    f16* W1t[3]; float* bias1[3]; unsigned char* W28[2];
    W1t[0] = (f16*)alloc(256 * 128 * 2);
    W1t[1] = (f16*)alloc(256 * 256 * 2);
    W1t[2] = (f16*)alloc(256 * 256 * 2);
    for (int l = 0; l < 2; ++l) W28[l] = (unsigned char*)alloc(256 * 256);
    for (int l = 0; l < 3; ++l) bias1[l] = (float*)alloc(256 * 4);
    float* W2o = (float*)alloc(512 * 4);
    float* bo  = (float*)alloc(2 * 4);
    unsigned* pairs = (unsigned*)alloc((size_t)NBUCK * BSTRIDE * 4);
    int* nb     = (int*)alloc(NBUCK * 4);
    int* bbase  = (int*)alloc(NBUCK * 4);
    int* rowptr = (int*)alloc((size_t)(N_NODES + 1) * 4);
    int* colidx = (int*)alloc((size_t)N_EDGES * 4);

    // CSR build
    hipMemsetAsync(nb, 0, NBUCK * 4, stream);
    k_bucketA<<<(N_EDGES + 4095) / 4096, 256, 0, stream>>>(esrc, edst, pairs, nb, N_EDGES);
    k_scan196<<<1, 256, 0, stream>>>(nb, bbase, rowptr + N_NODES);
    k_bucketB<<<NBUCK, 256, 0, stream>>>(pairs, nb, bbase, rowptr, colidx);

    // dtype prep + weight folds
    k_cvt8<<<(N_NODES * 64 + 255) / 256, 256, 0, stream>>>((const float2*)x, x8, N_NODES * 64);
    k_foldw1<<<128, 256, 0, stream>>>(lw[0][0], lw[0][1], lw[0][2], lw[0][3], lw[0][4], lw[0][5], W1t[0], bias1[0], 128);
    k_foldw1<<<256, 256, 0, stream>>>(lw[1][0], lw[1][1], lw[1][2], lw[1][3], lw[1][4], lw[1][5], W1t[1], bias1[1], 256);
    k_foldw1<<<256, 256, 0, stream>>>(lw[2][0], lw[2][1], lw[2][2], lw[2][3], lw[2][4], lw[2][5], W1t[2], bias1[2], 256);
    k_transb8<<<256, 256, 0, stream>>>(lw[0][6], W28[0]);
    k_transb8<<<256, 256, 0, stream>>>(lw[1][6], W28[1]);
    k_fold2<<<1, 256, 0, stream>>>(lw[2][6], lw[2][7], outW, outB, W2o, bo);

    const int GG = MPAD / 128;
    const int WBLOCKS = (N_NODES + 3) / 4;

    // layer 1
    k_agg128<<<WBLOCKS, 256, 0, stream>>>(x8, rowptr, colidx, (unsigned*)z, N_NODES);
    k_layer<128><<<GG, 256, 0, stream>>>(z, W1t[0], bias1[0], W28[0], lw[0][7], h8);
    // layer 2
    k_agg256<<<WBLOCKS, 256, 0, stream>>>((const unsigned*)h8, rowptr, colidx, (uint2*)z, N_NODES);
    k_layer<256><<<GG, 256, 0, stream>>>(z, W1t[1], bias1[1], W28[1], lw[1][7], h8);
    // layer 3 (fused GEMM1 + head)
    k_agg256<<<WBLOCKS, 256, 0, stream>>>((const unsigned*)h8, rowptr, colidx, (uint2*)z, N_NODES);
    k_layer3<<<GG, 256, 0, stream>>>(z, W1t[2], bias1[2], W2o, bo, (float*)d_out);
}